// Round 10
// baseline (172.399 us; speedup 1.0000x reference)
//
#include <hip/hip_runtime.h>
#include <math.h>

#define Bn 16
#define Sn 1024
#define Hn 1024
static const size_t SH = (size_t)Sn * Hn;          // 1,048,576
static const size_t BSH = (size_t)Bn * Sn * Hn;    // 16,777,216

typedef __attribute__((ext_vector_type(8))) short short8;
typedef __attribute__((ext_vector_type(4))) float f32x4;

// async global->LDS, 16B per lane; LDS dest is wave-uniform base + lane*16
#define GLD16(gp, lp) __builtin_amdgcn_global_load_lds( \
    (const __attribute__((address_space(1))) void*)(gp), \
    (__attribute__((address_space(3))) void*)(lp), 16, 0, 0)

// round-to-nearest-even fp32 -> bf16
__device__ __forceinline__ short bfr(float f) {
  union { float f; unsigned u; } v; v.f = f;
  unsigned r = (v.u + 0x7FFFu + ((v.u >> 16) & 1u)) >> 16;
  return (short)r;
}
__device__ __forceinline__ float b2f(unsigned short u) {
  union { unsigned u; float f; } v; v.u = (unsigned)u << 16; return v.f;
}
__device__ __forceinline__ short8 cvt8(float4 x, float4 y) {
  short8 r;
  r[0] = bfr(x.x); r[1] = bfr(x.y); r[2] = bfr(x.z); r[3] = bfr(x.w);
  r[4] = bfr(y.x); r[5] = bfr(y.y); r[6] = bfr(y.z); r[7] = bfr(y.w);
  return r;
}

// 8-granule swizzle: storage slot of logical granule g in row `row` is
// g ^ (row&7) within each 8-granule (64-element) k-block. Involution.
__device__ __forceinline__ int swz8(int row, int g) {
  return (g & ~7) | ((g & 7) ^ (row & 7));
}

// ---------------------------------------------------------------------------
// fused_cvt: enc[b][s][h] -> enc_bf (bf16, swz8 rows)  AND  encT (swz8 rows)
// ---------------------------------------------------------------------------
__global__ __launch_bounds__(256) void fused_cvt_kernel(const float* __restrict__ enc,
                                                        short* __restrict__ enc_bf,
                                                        short* __restrict__ encT) {
  __shared__ float tile[64][65];
  const int b = blockIdx.z;
  const int s0 = blockIdx.y * 64, h0 = blockIdx.x * 64;
  const int t = threadIdx.x;
  const int tr = t >> 4, tc = t & 15;
  const float* src = enc + (size_t)b * SH;
#pragma unroll
  for (int i = 0; i < 4; ++i) {
    const int s = i * 16 + tr;
    const float4 v = *(const float4*)(src + (size_t)(s0 + s) * 1024 + h0 + tc * 4);
    tile[s][tc * 4 + 0] = v.x; tile[s][tc * 4 + 1] = v.y;
    tile[s][tc * 4 + 2] = v.z; tile[s][tc * 4 + 3] = v.w;
  }
  __syncthreads();
  {
    const int rloc = t >> 2;
    const int rg = b * 1024 + s0 + rloc;
#pragma unroll
    for (int jj = 0; jj < 2; ++jj) {
      const int jloc = (t & 3) * 2 + jj;
      const int slot = jloc ^ (rg & 7);
      const float4 x = *(const float4*)&tile[rloc][jloc * 8];
      const float4 y = *(const float4*)&tile[rloc][jloc * 8 + 4];
      *(short8*)(enc_bf + (size_t)rg * 1024 + h0 + slot * 8) = cvt8(x, y);
    }
  }
  {
    const int hr = t >> 2, cs = t & 3;
    const int h = h0 + hr;
#pragma unroll
    for (int blk = 0; blk < 2; ++blk) {
      const int sg = blk * 4 + cs;
      const int gl = (s0 >> 3) + sg;
      const int gst = swz8(h, gl);
      short8 pk;
#pragma unroll
      for (int j = 0; j < 8; ++j) pk[j] = bfr(tile[sg * 8 + j][hr]);
      *(short8*)(encT + (size_t)b * SH + (size_t)h * 1024 + gst * 8) = pk;
    }
  }
}

// ---------------------------------------------------------------------------
// cvt_enc (fallback): enc -> enc_bf, swz8
// ---------------------------------------------------------------------------
__global__ __launch_bounds__(256) void cvt_enc_kernel(const float* __restrict__ enc,
                                                      short* __restrict__ enc_bf) {
  const int g = blockIdx.x * 256 + threadIdx.x;
  const int row = g >> 7;
  const int cs = g & 127;
  const float4 x = *(const float4*)(enc + (size_t)row * 1024 + cs * 8);
  const float4 y = *(const float4*)(enc + (size_t)row * 1024 + cs * 8 + 4);
  *(short8*)(enc_bf + (size_t)row * 1024 + swz8(row, cs) * 8) = cvt8(x, y);
}

// ---------------------------------------------------------------------------
// cvt_w2: W_attn[h][1024..2047] -> W2_bf[h][k] bf16, swz8
// ---------------------------------------------------------------------------
__global__ __launch_bounds__(256) void cvt_w2_kernel(const float* __restrict__ W_attn,
                                                     short* __restrict__ W2_bf) {
  const int g = blockIdx.x * 256 + threadIdx.x;
  const int h = g >> 7;
  const int cs = g & 127;
  const float4 x = *(const float4*)(W_attn + (size_t)h * 2048 + 1024 + cs * 8);
  const float4 y = *(const float4*)(W_attn + (size_t)h * 2048 + 1024 + cs * 8 + 4);
  *(short8*)(W2_bf + (size_t)h * 1024 + swz8(h, cs) * 8) = cvt8(x, y);
}

// ---------------------------------------------------------------------------
// c1: c1[b,h] = ht[b,:] . W_attn[h, 0:H] + b_attn[h]   (grid Hn/4)
// ---------------------------------------------------------------------------
__global__ __launch_bounds__(256) void c1_kernel(const float* __restrict__ ht,
                                                 const float* __restrict__ W_attn,
                                                 const float* __restrict__ b_attn,
                                                 float* __restrict__ c1) {
  __shared__ float hts[16384];
  const int t = threadIdx.x;
#pragma unroll
  for (int i = 0; i < 16; ++i)
    *(float4*)&hts[i * 1024 + t * 4] = *(const float4*)&ht[i * 1024 + t * 4];
  __syncthreads();
  const int h = blockIdx.x * 4 + (t >> 6);
  const int lane = t & 63;
  const float* w = W_attn + (size_t)h * 2048;
  float s[16];
#pragma unroll
  for (int b = 0; b < 16; ++b) s[b] = 0.f;
  for (int k = lane; k < 1024; k += 64) {
    const float wv = w[k];
#pragma unroll
    for (int b = 0; b < 16; ++b) s[b] = fmaf(wv, hts[b * 1024 + k], s[b]);
  }
#pragma unroll
  for (int b = 0; b < 16; ++b) {
    float v = s[b];
#pragma unroll
    for (int off = 32; off; off >>= 1) v += __shfl_down(v, off, 64);
    if (lane == 0) c1[b * 1024 + h] = v + b_attn[h];
  }
}

// ---------------------------------------------------------------------------
// GEMM1 (R7-proven config): Xbf = bf16(exp(tanh(enc_bf . W2_bf^T + c1)))
// [swz8 layout] + atomic column sums.  128x128 tile, 256 thr, 32KB LDS,
// GLD16 BK=64 2-barrier loop -> 4-5 blocks/CU so the heavy epilogue hides
// under other blocks' MFMA (this beat the 8-phase 1-block/CU config).
// ---------------------------------------------------------------------------
__global__ __launch_bounds__(256) void energy_v3(const short* __restrict__ enc_bf,
                                                 const short* __restrict__ W2_bf,
                                                 const float* __restrict__ c1,
                                                 short* __restrict__ Xbf,
                                                 float* __restrict__ colsum) {
  __shared__ __align__(16) short SMEM[2 * 128 * 64];   // 32 KB
  short* Ast = SMEM;
  short* Bst = SMEM + 128 * 64;
  const int flat = blockIdx.x + (blockIdx.y << 3) + (blockIdx.z << 6);
  const int swz = (flat & 7) * 128 + (flat >> 3);
  const int b = swz >> 6;
  const int row0 = ((swz >> 3) & 7) * 128;
  const int col0 = (swz & 7) * 128;
  const int t = threadIdx.x;
  const int l = t & 63;
  const int w = t >> 6;
  const int wr = w >> 1, wc = w & 1;
  const int fr = l & 15, kg = l >> 4;

  const short* Abase = enc_bf + (size_t)b * SH + (size_t)(row0 + w * 32 + (l >> 3)) * 1024 + (l & 7) * 8;
  const short* Bbase = W2_bf + (size_t)(col0 + w * 32 + (l >> 3)) * 1024 + (l & 7) * 8;
  short* Alds = Ast + w * 2048;
  short* Blds = Bst + w * 2048;

  f32x4 acc[4][4] = {};

  for (int k0 = 0; k0 < 1024; k0 += 64) {
#pragma unroll
    for (int j = 0; j < 4; ++j) {
      GLD16(Abase + k0 + j * 8 * 1024, Alds + j * 512);
      GLD16(Bbase + k0 + j * 8 * 1024, Blds + j * 512);
    }
    __syncthreads();
#pragma unroll
    for (int kk = 0; kk < 2; ++kk) {
      short8 af[4], bf4[4];
#pragma unroll
      for (int m = 0; m < 4; ++m) {
        const int r = wr * 64 + m * 16 + fr;
        af[m] = *(const short8*)&Ast[r * 64 + (((kk * 4 + kg) ^ (r & 7)) << 3)];
      }
#pragma unroll
      for (int n = 0; n < 4; ++n) {
        const int r = wc * 64 + n * 16 + fr;
        bf4[n] = *(const short8*)&Bst[r * 64 + (((kk * 4 + kg) ^ (r & 7)) << 3)];
      }
#pragma unroll
      for (int m = 0; m < 4; ++m)
#pragma unroll
        for (int n = 0; n < 4; ++n)
          acc[m][n] = __builtin_amdgcn_mfma_f32_16x16x32_bf16(af[m], bf4[n], acc[m][n], 0, 0, 0);
    }
    __syncthreads();
  }

  // epilogue: X = exp(tanh(acc+c1)); obuf bf16 (swz8-composed); colsum atomics
  unsigned short* obuf = (unsigned short*)SMEM;  // 128x128 ushort = 32 KB
#pragma unroll
  for (int n = 0; n < 4; ++n) {
    const int col_loc = wc * 64 + n * 16 + fr;
    const float c1v = c1[b * 1024 + col0 + col_loc];
    float csum = 0.f;
#pragma unroll
    for (int m = 0; m < 4; ++m) {
      const int rbase = wr * 64 + m * 16 + kg * 4;
#pragma unroll
      for (int r = 0; r < 4; ++r) {
        const float x = acc[m][n][r] + c1v;
        const float e = __expf(2.f * x);
        const float X = __expf((e - 1.f) / (e + 1.f));
        csum += X;
        const int row = rbase + r;
        obuf[row * 128 + (col_loc ^ ((row & 7) << 3))] = (unsigned short)bfr(X);
      }
    }
    csum += __shfl_xor(csum, 16);
    csum += __shfl_xor(csum, 32);
    if (l < 16) atomicAdd(&colsum[b * 1024 + col0 + col_loc], csum);
  }
  __syncthreads();
  // linear copy-out: LDS slot j -> global slot j (composes to swz8 layout)
  const int orow = t >> 1;
  short* gdst = Xbf + (size_t)b * SH + (size_t)(row0 + orow) * 1024 + col0;
#pragma unroll
  for (int j = 0; j < 8; ++j) {
    const int slot = (t & 1) * 8 + j;
    *(short8*)(gdst + slot * 8) = *(short8*)&obuf[orow * 128 + slot * 8];
  }
}

// ===========================================================================
// 8-phase 256x256 GEMM template (m201-style, plain HIP) — used by context8.
// 512 thr = 8 waves (2 wr x 4 wc); BK=64; LDS 128KB = 2 dbuf x (A 32K + B 32K).
// Stage schedule (tile kt): p0->B1(kt+1), p1->A1(kt+1), p2->A0(kt+2),
// p3->B0(kt+2). vmcnt(4) once per tile; raw barriers keep stages in flight.
// Global operands swz8-pre-swizzled; GLD16 writes LDS linearly; reads XOR.
// ===========================================================================
#define STAGE_A(kt, mh) do {                                              \
  const int p_ = (kt) & 1;                                                \
  _Pragma("unroll") for (int ld_ = 0; ld_ < 2; ++ld_) {                   \
    const int rl_ = (ld_ * 8 + wid) * 8 + (l >> 3);                       \
    GLD16(Ag + (size_t)((rl_ >> 6) * 128 + (mh) * 64 + (rl_ & 63)) * 1024 \
             + (kt) * 64 + (l & 7) * 8,                                   \
          &lds[p_ * 32768 + (mh) * 8192 + (ld_ * 8 + wid) * 512]);        \
  } } while (0)

#define STAGE_B(kt, nh) do {                                              \
  const int p_ = (kt) & 1;                                                \
  _Pragma("unroll") for (int ld_ = 0; ld_ < 2; ++ld_) {                   \
    const int rl_ = (ld_ * 8 + wid) * 8 + (l >> 3);                       \
    GLD16(Bg + (size_t)((rl_ >> 5) * 64 + (nh) * 32 + (rl_ & 31)) * 1024  \
             + (kt) * 64 + (l & 7) * 8,                                   \
          &lds[16384 + p_ * 32768 + (nh) * 8192 + (ld_ * 8 + wid) * 512]); \
  } } while (0)

#define PHASE(mh, nh, ...) do {                                           \
  if ((nh) == 0) {                                                        \
    _Pragma("unroll") for (int mi = 0; mi < 4; ++mi)                      \
      _Pragma("unroll") for (int ks = 0; ks < 2; ++ks)                    \
        afr[mi][ks] = *(const short8*)&lds[ab + (mh) * 8192               \
            + (wr * 64 + mi * 16 + fr) * 64                               \
            + (((ks * 4 + kg) ^ (fr & 7)) << 3)];                         \
  }                                                                       \
  _Pragma("unroll") for (int ni = 0; ni < 2; ++ni)                        \
    _Pragma("unroll") for (int ks = 0; ks < 2; ++ks)                      \
      bfrg[ni][ks] = *(const short8*)&lds[bb + (nh) * 8192                \
          + (wc * 32 + ni * 16 + fr) * 64                                 \
          + (((ks * 4 + kg) ^ (fr & 7)) << 3)];                           \
  __VA_ARGS__;                                                            \
  __builtin_amdgcn_s_barrier();                                           \
  __builtin_amdgcn_s_setprio(1);                                          \
  _Pragma("unroll") for (int mi = 0; mi < 4; ++mi)                        \
    _Pragma("unroll") for (int ni = 0; ni < 2; ++ni)                      \
      _Pragma("unroll") for (int ks = 0; ks < 2; ++ks)                    \
        acc[(mh) * 4 + mi][(nh) * 2 + ni] =                               \
            __builtin_amdgcn_mfma_f32_16x16x32_bf16(afr[mi][ks],          \
                bfrg[ni][ks], acc[(mh) * 4 + mi][(nh) * 2 + ni], 0, 0, 0); \
  __builtin_amdgcn_s_setprio(0);                                          \
} while (0)

#define KLOOP_8PHASE()                                                    \
  STAGE_A(0, 0); STAGE_B(0, 0); STAGE_B(0, 1); STAGE_A(0, 1);             \
  STAGE_A(1, 0); STAGE_B(1, 0);                                           \
  asm volatile("s_waitcnt vmcnt(4)" ::: "memory");                        \
  __builtin_amdgcn_s_barrier();                                           \
  _Pragma("unroll 2") for (int kt = 0; kt < 16; ++kt) {                   \
    const int ab = (kt & 1) * 32768;                                      \
    const int bb = 16384 + (kt & 1) * 32768;                              \
    PHASE(0, 0, if (kt < 15) STAGE_B(kt + 1, 1));                         \
    __builtin_amdgcn_s_barrier();                                         \
    PHASE(0, 1, if (kt < 15) STAGE_A(kt + 1, 1));                         \
    __builtin_amdgcn_s_barrier();                                         \
    PHASE(1, 0, if (kt < 14) STAGE_A(kt + 2, 0));                         \
    __builtin_amdgcn_s_barrier();                                         \
    PHASE(1, 1, if (kt < 14) STAGE_B(kt + 2, 0));                         \
    if (kt < 14) asm volatile("s_waitcnt vmcnt(4)" ::: "memory");         \
    else         asm volatile("s_waitcnt vmcnt(0)" ::: "memory");         \
    __builtin_amdgcn_s_barrier();                                         \
  }

// ---------------------------------------------------------------------------
// GEMM2 (8-phase): ctx = awbf . encT^T
// ---------------------------------------------------------------------------
__global__ __launch_bounds__(512) void context8(const short* __restrict__ awbf,
                                                const short* __restrict__ encT,
                                                float* __restrict__ ctx) {
  __shared__ __align__(16) short lds[65536];
  const int flat = blockIdx.x;
  const int id = (flat & 7) * 32 + (flat >> 3);
  const int b = id >> 4;
  const int row0 = ((id >> 2) & 3) * 256;
  const int col0 = (id & 3) * 256;
  const int t = threadIdx.x;
  const int wid = t >> 6, l = t & 63;
  const int wr = wid >> 2, wc = wid & 3;
  const int fr = l & 15, kg = l >> 4;

  const short* Ag = awbf + (size_t)b * SH + (size_t)row0 * 1024;
  const short* Bg = encT + (size_t)b * SH + (size_t)col0 * 1024;

  f32x4 acc[8][4] = {};
  short8 afr[4][2], bfrg[2][2];

  KLOOP_8PHASE();

  float* Cb = ctx + (size_t)b * SH;
#pragma unroll
  for (int n = 0; n < 4; ++n) {
    const int col = col0 + wc * 64 + n * 16 + fr;
#pragma unroll
    for (int m = 0; m < 8; ++m) {
#pragma unroll
      for (int r = 0; r < 4; ++r)
        Cb[(size_t)(row0 + wr * 128 + m * 16 + kg * 4 + r) * 1024 + col] = acc[m][n][r];
    }
  }
}

// ---------------------------------------------------------------------------
// rcp: colinv = 1/colsum
// ---------------------------------------------------------------------------
__global__ __launch_bounds__(256) void rcp_kernel(const float* __restrict__ cs,
                                                  float* __restrict__ ci) {
  const int i = blockIdx.x * 256 + threadIdx.x;
  ci[i] = 1.0f / cs[i];
}

// ---------------------------------------------------------------------------
// scale: awbf = bf16(Xbf * colinv) in-place (swz8, same slot), aw fp32 out
// ---------------------------------------------------------------------------
__global__ __launch_bounds__(256) void scale_v1(short* __restrict__ Xbf,
                                                const float* __restrict__ colinv,
                                                float* __restrict__ aw) {
  const size_t gid = (size_t)blockIdx.x * 256 + threadIdx.x;
  const int rg = (int)(gid >> 7);
  const int ss = (int)(gid & 127);
  const int b = rg >> 10;
  const int gl = (ss & ~7) | ((ss & 7) ^ (rg & 7));   // logical granule
  const int h0 = gl * 8;
  short* p = Xbf + (size_t)rg * 1024 + ss * 8;
  const short8 v = *(const short8*)p;
  const float4 ci0 = *(const float4*)(colinv + (b << 10) + h0);
  const float4 ci1 = *(const float4*)(colinv + (b << 10) + h0 + 4);
  float f[8];
  f[0] = b2f((unsigned short)v[0]) * ci0.x; f[1] = b2f((unsigned short)v[1]) * ci0.y;
  f[2] = b2f((unsigned short)v[2]) * ci0.z; f[3] = b2f((unsigned short)v[3]) * ci0.w;
  f[4] = b2f((unsigned short)v[4]) * ci1.x; f[5] = b2f((unsigned short)v[5]) * ci1.y;
  f[6] = b2f((unsigned short)v[6]) * ci1.z; f[7] = b2f((unsigned short)v[7]) * ci1.w;
  float4 o0 = {f[0], f[1], f[2], f[3]};
  float4 o1 = {f[4], f[5], f[6], f[7]};
  *(float4*)(aw + (size_t)rg * 1024 + h0) = o0;
  *(float4*)(aw + (size_t)rg * 1024 + h0 + 4) = o1;
  short8 r;
#pragma unroll
  for (int j = 0; j < 8; ++j) r[j] = bfr(f[j]);
  *(short8*)p = r;
}

// ===========================================================================
// Fallback path (no workspace needed): R6/R7-proven kernels
// ===========================================================================
__global__ __launch_bounds__(256) void energy_mfma4(const short* __restrict__ enc_bf,
                                                    const short* __restrict__ W2_bf,
                                                    const float* __restrict__ c1,
                                                    float* __restrict__ X) {
  __shared__ __align__(16) short Ast[128 * 64];
  __shared__ __align__(16) short Bst[128 * 64];
  const int flat = blockIdx.x + (blockIdx.y << 3) + (blockIdx.z << 6);
  const int swz = (flat & 7) * 128 + (flat >> 3);
  const int b = swz >> 6;
  const int row0 = ((swz >> 3) & 7) * 128;
  const int col0 = (swz & 7) * 128;
  const int t = threadIdx.x;
  const int l = t & 63;
  const int w = t >> 6;
  const int wr = w >> 1, wc = w & 1;
  const int fr = l & 15, kg = l >> 4;

  const short* Abase = enc_bf + (size_t)b * SH + (size_t)(row0 + w * 32 + (l >> 3)) * 1024 + (l & 7) * 8;
  const short* Bbase = W2_bf + (size_t)(col0 + w * 32 + (l >> 3)) * 1024 + (l & 7) * 8;
  short* Alds = Ast + w * 2048;
  short* Blds = Bst + w * 2048;

  f32x4 acc[4][4] = {};

  for (int k0 = 0; k0 < 1024; k0 += 64) {
#pragma unroll
    for (int j = 0; j < 4; ++j) {
      GLD16(Abase + k0 + j * 8 * 1024, Alds + j * 512);
      GLD16(Bbase + k0 + j * 8 * 1024, Blds + j * 512);
    }
    __syncthreads();
#pragma unroll
    for (int kk = 0; kk < 2; ++kk) {
      short8 af[4], bf4[4];
#pragma unroll
      for (int m = 0; m < 4; ++m) {
        const int r = wr * 64 + m * 16 + fr;
        af[m] = *(const short8*)&Ast[r * 64 + (((kk * 4 + kg) ^ (r & 7)) << 3)];
      }
#pragma unroll
      for (int n = 0; n < 4; ++n) {
        const int r = wc * 64 + n * 16 + fr;
        bf4[n] = *(const short8*)&Bst[r * 64 + (((kk * 4 + kg) ^ (r & 7)) << 3)];
      }
#pragma unroll
      for (int m = 0; m < 4; ++m)
#pragma unroll
        for (int n = 0; n < 4; ++n)
          acc[m][n] = __builtin_amdgcn_mfma_f32_16x16x32_bf16(af[m], bf4[n], acc[m][n], 0, 0, 0);
    }
    __syncthreads();
  }

  float* Xb = X + (size_t)b * SH;
#pragma unroll
  for (int n = 0; n < 4; ++n) {
    const int col = col0 + wc * 64 + n * 16 + fr;
    const float c1v = c1[b * 1024 + col];
#pragma unroll
    for (int m = 0; m < 4; ++m) {
      const int r0 = row0 + wr * 64 + m * 16 + kg * 4;
#pragma unroll
      for (int r = 0; r < 4; ++r) {
        const float x = acc[m][n][r] + c1v;
        const float e = __expf(2.f * x);
        Xb[(size_t)(r0 + r) * 1024 + col] = __expf((e - 1.f) / (e + 1.f));
      }
    }
  }
}

__global__ __launch_bounds__(256) void norm_kernel(float* __restrict__ X) {
  const int b = blockIdx.x >> 4;
  const int hg = blockIdx.x & 15;
  const int l = threadIdx.x & 63;
  const int sg = threadIdx.x >> 6;
  float* col = X + (size_t)b * SH + hg * 64 + l;
  const int s0 = sg * 256;
  float sum = 0.f;
#pragma unroll 8
  for (int s = s0; s < s0 + 256; ++s) sum += col[(size_t)s * 1024];
  __shared__ float red[4][64];
  red[sg][l] = sum;
  __syncthreads();
  const float inv = 1.f / (red[0][l] + red[1][l] + red[2][l] + red[3][l]);
#pragma unroll 8
  for (int s = s0; s < s0 + 256; ++s) col[(size_t)s * 1024] *= inv;
}

// self-contained fallback GEMM2 (raw fp32 inputs)
__global__ __launch_bounds__(256) void context_mfma(const float* __restrict__ aw,
                                                    const float* __restrict__ enc,
                                                    float* __restrict__ ctx) {
  __shared__ __align__(16) short Ast[128 * 32];
  __shared__ __align__(16) short Bst[128 * 32];
  const int b = blockIdx.z;
  const int row0 = blockIdx.y * 128;
  const int col0 = blockIdx.x * 128;
  const int t = threadIdx.x;
  const int l = t & 63;
  const int w = t >> 6;
  const int wr = w >> 1, wc = w & 1;
  const int fr = l & 15, kg = l >> 4;

  const int sr = t >> 1;
  const int sc0 = (t & 1) * 2;
  const float* arow = aw + (size_t)b * SH + (size_t)(row0 + sr) * 1024;
  const int bcol = t & 127;
  const int kb0 = (t >> 7) * 2;
  const float* bcolp = enc + (size_t)b * SH + col0 + bcol;

  f32x4 acc[4][4] = {};

#define LSLOT(r, g) ((r) * 32 + (((g) ^ (((r) >> 1) & 3)) << 3))
  for (int k0 = 0; k0 < 1024; k0 += 32) {
    const float4 a0 = *(const float4*)(arow + k0 + sc0 * 8);
    const float4 a1 = *(const float4*)(arow + k0 + sc0 * 8 + 4);
    const float4 a2 = *(const float4*)(arow + k0 + sc0 * 8 + 8);
    const float4 a3 = *(const float4*)(arow + k0 + sc0 * 8 + 12);
    float bv[2][8];
#pragma unroll
    for (int j = 0; j < 2; ++j)
#pragma unroll
      for (int i = 0; i < 8; ++i)
        bv[j][i] = bcolp[(size_t)(k0 + (kb0 + j) * 8 + i) * 1024];
    __syncthreads();
    *(short8*)&Ast[LSLOT(sr, sc0)]     = cvt8(a0, a1);
    *(short8*)&Ast[LSLOT(sr, sc0 + 1)] = cvt8(a2, a3);
#pragma unroll
    for (int j = 0; j < 2; ++j) {
      short8 pk;
#pragma unroll
      for (int i = 0; i < 8; ++i) pk[i] = bfr(bv[j][i]);
      *(short8*)&Bst[LSLOT(bcol, kb0 + j)] = pk;
    }
    __syncthreads();
    short8 af[4], bf4[4];
#pragma unroll
    for (int m = 0; m < 4; ++m) {
      const int r = wr * 64 + m * 16 + fr;
      af[m] = *(const short8*)&Ast[LSLOT(r, kg)];
    }
#pragma unroll
    for (int n = 0; n < 4; ++n) {
      const int r = wc * 64 + n * 16 + fr;
      bf4[n] = *(const short8*)&Bst[LSLOT(r, kg)];
    }
#pragma unroll
    for (int m = 0; m < 4; ++m)
#pragma unroll
      for (int n = 0; n < 4; ++n)
        acc[m][n] = __builtin_amdgcn_mfma_f32_16x16x32_bf16(af[m], bf4[n], acc[m][n], 0, 0, 0);
  }

  float* Cb = ctx + (size_t)b * SH;
#pragma unroll
  for (int n = 0; n < 4; ++n) {
    const int col = col0 + wc * 64 + n * 16 + fr;
#pragma unroll
    for (int m = 0; m < 4; ++m) {
      const int r0 = row0 + wr * 64 + m * 16 + kg * 4;
#pragma unroll
      for (int r = 0; r < 4; ++r)
        Cb[(size_t)(r0 + r) * 1024 + col] = acc[m][n][r];
    }
  }
}

// ---------------------------------------------------------------------------
extern "C" void kernel_launch(void* const* d_in, const int* in_sizes, int n_in,
                              void* d_out, int out_size, void* d_ws, size_t ws_size,
                              hipStream_t stream) {
  (void)in_sizes; (void)n_in; (void)out_size;
  const float* ht     = (const float*)d_in[0];
  const float* enc    = (const float*)d_in[1];
  const float* W_attn = (const float*)d_in[2];
  const float* b_attn = (const float*)d_in[3];
  // d_in[4] (W_v) is dead code in the reference

  float* ctx = (float*)d_out;          // [B,S,H] context (written last)
  float* aw  = ctx + BSH;              // [B,S,H] attention_weights

  // scratch parked inside the (dead-until-GEMM2) ctx region:
  short* enc_bf = (short*)ctx;                         // 32 MB, bf16 swz8
  short* W2_bf  = (short*)(ctx + 8388608);             // 2 MB
  float* c1f    = ctx + 8912896;                       // 64 KB
  float* colsum = c1f + 16384;                         // 64 KB
  float* colinv = c1f + 32768;                         // 64 KB

  const bool ws2 = ws_size >= ((size_t)64 << 20);      // encT + Xbf
  short* encT = (short*)d_ws;                          // 32 MB
  short* Xbf  = (short*)((char*)d_ws + ((size_t)32 << 20));  // 32 MB

  cvt_w2_kernel<<<512, 256, 0, stream>>>(W_attn, W2_bf);
  c1_kernel<<<Hn / 4, 256, 0, stream>>>(ht, W_attn, b_attn, c1f);

  if (ws2) {
    dim3 gt(16, 16, Bn);
    fused_cvt_kernel<<<gt, 256, 0, stream>>>(enc, enc_bf, encT);
    hipMemsetAsync(colsum, 0, 65536, stream);
    dim3 g(8, 8, Bn);
    energy_v3<<<g, 256, 0, stream>>>(enc_bf, W2_bf, c1f, Xbf, colsum);
    rcp_kernel<<<64, 256, 0, stream>>>(colsum, colinv);
    scale_v1<<<8192, 256, 0, stream>>>(Xbf, colinv, aw);
    context8<<<256, 512, 0, stream>>>(Xbf, encT, ctx);
  } else {
    cvt_enc_kernel<<<8192, 256, 0, stream>>>(enc, enc_bf);
    dim3 g(8, 8, Bn);
    energy_mfma4<<<g, 256, 0, stream>>>(enc_bf, W2_bf, c1f, aw);
    norm_kernel<<<Bn * 16, 256, 0, stream>>>(aw);
    context_mfma<<<g, 256, 0, stream>>>(aw, enc, ctx);
  }
}

// Round 11
// 162.763 us; speedup vs baseline: 1.0592x; 1.0592x over previous
//
#include <hip/hip_runtime.h>
#include <math.h>

#define Bn 16
#define Sn 1024
#define Hn 1024
static const size_t SH = (size_t)Sn * Hn;          // 1,048,576
static const size_t BSH = (size_t)Bn * Sn * Hn;    // 16,777,216

typedef __attribute__((ext_vector_type(8))) short short8;
typedef __attribute__((ext_vector_type(4))) float f32x4;

// async global->LDS, 16B per lane; LDS dest is wave-uniform base + lane*16
#define GLD16(gp, lp) __builtin_amdgcn_global_load_lds( \
    (const __attribute__((address_space(1))) void*)(gp), \
    (__attribute__((address_space(3))) void*)(lp), 16, 0, 0)

// round-to-nearest-even fp32 -> bf16
__device__ __forceinline__ short bfr(float f) {
  union { float f; unsigned u; } v; v.f = f;
  unsigned r = (v.u + 0x7FFFu + ((v.u >> 16) & 1u)) >> 16;
  return (short)r;
}
__device__ __forceinline__ float b2f(unsigned short u) {
  union { unsigned u; float f; } v; v.u = (unsigned)u << 16; return v.f;
}
__device__ __forceinline__ short8 cvt8(float4 x, float4 y) {
  short8 r;
  r[0] = bfr(x.x); r[1] = bfr(x.y); r[2] = bfr(x.z); r[3] = bfr(x.w);
  r[4] = bfr(y.x); r[5] = bfr(y.y); r[6] = bfr(y.z); r[7] = bfr(y.w);
  return r;
}
// X = exp(tanh(x)) with fast rcp: tanh = 1 - 2/(e^{2x}+1)
__device__ __forceinline__ float exptanh(float x) {
  const float e = __expf(2.f * x);
  const float r = __builtin_amdgcn_rcpf(e + 1.f);
  return __expf(1.f - 2.f * r);
}

// 8-granule swizzle: storage slot of logical granule g in row `row` is
// g ^ (row&7) within each 8-granule (64-element) k-block. Involution.
__device__ __forceinline__ int swz8(int row, int g) {
  return (g & ~7) | ((g & 7) ^ (row & 7));
}

// ---------------------------------------------------------------------------
// fused_cvt: enc[b][s][h] -> enc_bf (bf16, swz8 rows)  AND  encT (swz8 rows)
// ---------------------------------------------------------------------------
__global__ __launch_bounds__(256) void fused_cvt_kernel(const float* __restrict__ enc,
                                                        short* __restrict__ enc_bf,
                                                        short* __restrict__ encT) {
  __shared__ float tile[64][65];
  const int b = blockIdx.z;
  const int s0 = blockIdx.y * 64, h0 = blockIdx.x * 64;
  const int t = threadIdx.x;
  const int tr = t >> 4, tc = t & 15;
  const float* src = enc + (size_t)b * SH;
#pragma unroll
  for (int i = 0; i < 4; ++i) {
    const int s = i * 16 + tr;
    const float4 v = *(const float4*)(src + (size_t)(s0 + s) * 1024 + h0 + tc * 4);
    tile[s][tc * 4 + 0] = v.x; tile[s][tc * 4 + 1] = v.y;
    tile[s][tc * 4 + 2] = v.z; tile[s][tc * 4 + 3] = v.w;
  }
  __syncthreads();
  {
    const int rloc = t >> 2;
    const int rg = b * 1024 + s0 + rloc;
#pragma unroll
    for (int jj = 0; jj < 2; ++jj) {
      const int jloc = (t & 3) * 2 + jj;
      const int slot = jloc ^ (rg & 7);
      const float4 x = *(const float4*)&tile[rloc][jloc * 8];
      const float4 y = *(const float4*)&tile[rloc][jloc * 8 + 4];
      *(short8*)(enc_bf + (size_t)rg * 1024 + h0 + slot * 8) = cvt8(x, y);
    }
  }
  {
    const int hr = t >> 2, cs = t & 3;
    const int h = h0 + hr;
#pragma unroll
    for (int blk = 0; blk < 2; ++blk) {
      const int sg = blk * 4 + cs;
      const int gl = (s0 >> 3) + sg;
      const int gst = swz8(h, gl);
      short8 pk;
#pragma unroll
      for (int j = 0; j < 8; ++j) pk[j] = bfr(tile[sg * 8 + j][hr]);
      *(short8*)(encT + (size_t)b * SH + (size_t)h * 1024 + gst * 8) = pk;
    }
  }
}

// ---------------------------------------------------------------------------
// cvt_enc (fallback): enc -> enc_bf, swz8
// ---------------------------------------------------------------------------
__global__ __launch_bounds__(256) void cvt_enc_kernel(const float* __restrict__ enc,
                                                      short* __restrict__ enc_bf) {
  const int g = blockIdx.x * 256 + threadIdx.x;
  const int row = g >> 7;
  const int cs = g & 127;
  const float4 x = *(const float4*)(enc + (size_t)row * 1024 + cs * 8);
  const float4 y = *(const float4*)(enc + (size_t)row * 1024 + cs * 8 + 4);
  *(short8*)(enc_bf + (size_t)row * 1024 + swz8(row, cs) * 8) = cvt8(x, y);
}

// ---------------------------------------------------------------------------
// cvt_w2: W_attn[h][1024..2047] -> W2_bf[h][k] bf16, swz8
// ---------------------------------------------------------------------------
__global__ __launch_bounds__(256) void cvt_w2_kernel(const float* __restrict__ W_attn,
                                                     short* __restrict__ W2_bf) {
  const int g = blockIdx.x * 256 + threadIdx.x;
  const int h = g >> 7;
  const int cs = g & 127;
  const float4 x = *(const float4*)(W_attn + (size_t)h * 2048 + 1024 + cs * 8);
  const float4 y = *(const float4*)(W_attn + (size_t)h * 2048 + 1024 + cs * 8 + 4);
  *(short8*)(W2_bf + (size_t)h * 1024 + swz8(h, cs) * 8) = cvt8(x, y);
}

// ---------------------------------------------------------------------------
// c1: c1[b,h] = ht[b,:] . W_attn[h, 0:H] + b_attn[h]   (grid Hn/4)
// ---------------------------------------------------------------------------
__global__ __launch_bounds__(256) void c1_kernel(const float* __restrict__ ht,
                                                 const float* __restrict__ W_attn,
                                                 const float* __restrict__ b_attn,
                                                 float* __restrict__ c1) {
  __shared__ float hts[16384];
  const int t = threadIdx.x;
#pragma unroll
  for (int i = 0; i < 16; ++i)
    *(float4*)&hts[i * 1024 + t * 4] = *(const float4*)&ht[i * 1024 + t * 4];
  __syncthreads();
  const int h = blockIdx.x * 4 + (t >> 6);
  const int lane = t & 63;
  const float* w = W_attn + (size_t)h * 2048;
  float s[16];
#pragma unroll
  for (int b = 0; b < 16; ++b) s[b] = 0.f;
  for (int k = lane; k < 1024; k += 64) {
    const float wv = w[k];
#pragma unroll
    for (int b = 0; b < 16; ++b) s[b] = fmaf(wv, hts[b * 1024 + k], s[b]);
  }
#pragma unroll
  for (int b = 0; b < 16; ++b) {
    float v = s[b];
#pragma unroll
    for (int off = 32; off; off >>= 1) v += __shfl_down(v, off, 64);
    if (lane == 0) c1[b * 1024 + h] = v + b_attn[h];
  }
}

// ===========================================================================
// 8-phase 256x256 GEMM template (m201-style, plain HIP).
// 512 thr = 8 waves (2 wr x 4 wc); BK=64; LDS 128KB = 2 dbuf x (A 32K + B 32K).
// Stage schedule (tile kt): p0->B1(kt+1), p1->A1(kt+1), p2->A0(kt+2),
// p3->B0(kt+2). vmcnt(4) once per tile; raw barriers keep stages in flight.
// Global operands swz8-pre-swizzled; GLD16 writes LDS linearly; reads XOR.
// PROVEN race-free across graph replays (R9).
// ===========================================================================
#define STAGE_A(kt, mh) do {                                              \
  const int p_ = (kt) & 1;                                                \
  _Pragma("unroll") for (int ld_ = 0; ld_ < 2; ++ld_) {                   \
    const int rl_ = (ld_ * 8 + wid) * 8 + (l >> 3);                       \
    GLD16(Ag + (size_t)((rl_ >> 6) * 128 + (mh) * 64 + (rl_ & 63)) * 1024 \
             + (kt) * 64 + (l & 7) * 8,                                   \
          &lds[p_ * 32768 + (mh) * 8192 + (ld_ * 8 + wid) * 512]);        \
  } } while (0)

#define STAGE_B(kt, nh) do {                                              \
  const int p_ = (kt) & 1;                                                \
  _Pragma("unroll") for (int ld_ = 0; ld_ < 2; ++ld_) {                   \
    const int rl_ = (ld_ * 8 + wid) * 8 + (l >> 3);                       \
    GLD16(Bg + (size_t)((rl_ >> 5) * 64 + (nh) * 32 + (rl_ & 31)) * 1024  \
             + (kt) * 64 + (l & 7) * 8,                                   \
          &lds[16384 + p_ * 32768 + (nh) * 8192 + (ld_ * 8 + wid) * 512]); \
  } } while (0)

#define PHASE(mh, nh, ...) do {                                           \
  if ((nh) == 0) {                                                        \
    _Pragma("unroll") for (int mi = 0; mi < 4; ++mi)                      \
      _Pragma("unroll") for (int ks = 0; ks < 2; ++ks)                    \
        afr[mi][ks] = *(const short8*)&lds[ab + (mh) * 8192               \
            + (wr * 64 + mi * 16 + fr) * 64                               \
            + (((ks * 4 + kg) ^ (fr & 7)) << 3)];                         \
  }                                                                       \
  _Pragma("unroll") for (int ni = 0; ni < 2; ++ni)                        \
    _Pragma("unroll") for (int ks = 0; ks < 2; ++ks)                      \
      bfrg[ni][ks] = *(const short8*)&lds[bb + (nh) * 8192                \
          + (wc * 32 + ni * 16 + fr) * 64                                 \
          + (((ks * 4 + kg) ^ (fr & 7)) << 3)];                           \
  __VA_ARGS__;                                                            \
  __builtin_amdgcn_s_barrier();                                           \
  __builtin_amdgcn_s_setprio(1);                                          \
  _Pragma("unroll") for (int mi = 0; mi < 4; ++mi)                        \
    _Pragma("unroll") for (int ni = 0; ni < 2; ++ni)                      \
      _Pragma("unroll") for (int ks = 0; ks < 2; ++ks)                    \
        acc[(mh) * 4 + mi][(nh) * 2 + ni] =                               \
            __builtin_amdgcn_mfma_f32_16x16x32_bf16(afr[mi][ks],          \
                bfrg[ni][ks], acc[(mh) * 4 + mi][(nh) * 2 + ni], 0, 0, 0); \
  __builtin_amdgcn_s_setprio(0);                                          \
} while (0)

#define KLOOP_8PHASE()                                                    \
  STAGE_A(0, 0); STAGE_B(0, 0); STAGE_B(0, 1); STAGE_A(0, 1);             \
  STAGE_A(1, 0); STAGE_B(1, 0);                                           \
  asm volatile("s_waitcnt vmcnt(4)" ::: "memory");                        \
  __builtin_amdgcn_s_barrier();                                           \
  _Pragma("unroll 2") for (int kt = 0; kt < 16; ++kt) {                   \
    const int ab = (kt & 1) * 32768;                                      \
    const int bb = 16384 + (kt & 1) * 32768;                              \
    PHASE(0, 0, if (kt < 15) STAGE_B(kt + 1, 1));                         \
    __builtin_amdgcn_s_barrier();                                         \
    PHASE(0, 1, if (kt < 15) STAGE_A(kt + 1, 1));                         \
    __builtin_amdgcn_s_barrier();                                         \
    PHASE(1, 0, if (kt < 14) STAGE_A(kt + 2, 0));                         \
    __builtin_amdgcn_s_barrier();                                         \
    PHASE(1, 1, if (kt < 14) STAGE_B(kt + 2, 0));                         \
    if (kt < 14) asm volatile("s_waitcnt vmcnt(4)" ::: "memory");         \
    else         asm volatile("s_waitcnt vmcnt(0)" ::: "memory");         \
    __builtin_amdgcn_s_barrier();                                         \
  }

// ---------------------------------------------------------------------------
// GEMM1 (8-phase): Xbf = bf16(exp(tanh(enc_bf . W2_bf^T + c1))) [swz8 layout]
// + per-(row_blk,wr) partial column sums (no atomics, no init needed).
// ---------------------------------------------------------------------------
__global__ __launch_bounds__(512) void energy8(const short* __restrict__ enc_bf,
                                               const short* __restrict__ W2_bf,
                                               const float* __restrict__ c1,
                                               short* __restrict__ Xbf,
                                               float* __restrict__ part) {
  __shared__ __align__(16) short lds[65536];   // 128 KB
  const int flat = blockIdx.x;
  const int id = (flat & 7) * 32 + (flat >> 3);   // XCD-chunked (256 = 8*32)
  const int b = id >> 4;
  const int rb = (id >> 2) & 3;
  const int row0 = rb * 256;
  const int col0 = (id & 3) * 256;
  const int t = threadIdx.x;
  const int wid = t >> 6, l = t & 63;
  const int wr = wid >> 2, wc = wid & 3;
  const int fr = l & 15, kg = l >> 4;

  const short* Ag = enc_bf + (size_t)b * SH + (size_t)row0 * 1024;
  const short* Bg = W2_bf + (size_t)col0 * 1024;

  f32x4 acc[8][4] = {};
  short8 afr[4][2], bfrg[2][2];

  KLOOP_8PHASE();
  __syncthreads();   // full fence before LDS reuse

  // epilogue: X = exp(tanh(acc+c1)); obuf bf16 (swz8-composed);
  // partial colsum plane p = rb*2+wr (each slot written exactly once).
  unsigned short* obuf = (unsigned short*)lds;   // 256x256 ushort = 128 KB
  float* pplane = part + (size_t)(rb * 2 + wr) * 16384 + b * 1024 + col0;
#pragma unroll
  for (int n = 0; n < 4; ++n) {
    const int col_loc = wc * 64 + n * 16 + fr;
    const float c1v = c1[b * 1024 + col0 + col_loc];
    float csum = 0.f;
#pragma unroll
    for (int m = 0; m < 8; ++m) {
#pragma unroll
      for (int r = 0; r < 4; ++r) {
        const int row_loc = wr * 128 + m * 16 + kg * 4 + r;
        const float X = exptanh(acc[m][n][r] + c1v);
        csum += X;
        const int g = col_loc >> 3;
        const int sg = (g & ~7) | ((g & 7) ^ (row_loc & 7));
        obuf[row_loc * 256 + sg * 8 + (col_loc & 7)] = (unsigned short)bfr(X);
      }
    }
    csum += __shfl_xor(csum, 16);
    csum += __shfl_xor(csum, 32);
    if (l < 16) pplane[col_loc] = csum;
  }
  __syncthreads();
  // linear copy-out (swizzles compose to global swz8 layout)
  const int orow = t >> 1;
  short* gd = Xbf + (size_t)b * SH + (size_t)(row0 + orow) * 1024 + col0;
#pragma unroll
  for (int j = 0; j < 16; ++j) {
    const int ls = (t & 1) * 16 + j;
    *(short8*)(gd + ls * 8) = *(short8*)&obuf[orow * 256 + ls * 8];
  }
}

// ---------------------------------------------------------------------------
// GEMM2 (8-phase): ctx = awbf . encT^T
// ---------------------------------------------------------------------------
__global__ __launch_bounds__(512) void context8(const short* __restrict__ awbf,
                                                const short* __restrict__ encT,
                                                float* __restrict__ ctx) {
  __shared__ __align__(16) short lds[65536];
  const int flat = blockIdx.x;
  const int id = (flat & 7) * 32 + (flat >> 3);
  const int b = id >> 4;
  const int row0 = ((id >> 2) & 3) * 256;
  const int col0 = (id & 3) * 256;
  const int t = threadIdx.x;
  const int wid = t >> 6, l = t & 63;
  const int wr = wid >> 2, wc = wid & 3;
  const int fr = l & 15, kg = l >> 4;

  const short* Ag = awbf + (size_t)b * SH + (size_t)row0 * 1024;
  const short* Bg = encT + (size_t)b * SH + (size_t)col0 * 1024;

  f32x4 acc[8][4] = {};
  short8 afr[4][2], bfrg[2][2];

  KLOOP_8PHASE();

  float* Cb = ctx + (size_t)b * SH;
#pragma unroll
  for (int n = 0; n < 4; ++n) {
    const int col = col0 + wc * 64 + n * 16 + fr;
#pragma unroll
    for (int m = 0; m < 8; ++m) {
#pragma unroll
      for (int r = 0; r < 4; ++r)
        Cb[(size_t)(row0 + wr * 128 + m * 16 + kg * 4 + r) * 1024 + col] = acc[m][n][r];
    }
  }
}

// ---------------------------------------------------------------------------
// rcp: colinv[i] = 1 / sum_p part[p][i]   (8 planes; 64 blocks)
// ---------------------------------------------------------------------------
__global__ __launch_bounds__(256) void rcp_kernel(const float* __restrict__ part,
                                                  float* __restrict__ ci) {
  const int i = blockIdx.x * 256 + threadIdx.x;
  float s = 0.f;
#pragma unroll
  for (int p = 0; p < 8; ++p) s += part[p * 16384 + i];
  ci[i] = 1.0f / s;
}

// ---------------------------------------------------------------------------
// scale: awbf = bf16(Xbf * colinv) in-place (swz8, same slot), aw fp32 out
// ---------------------------------------------------------------------------
__global__ __launch_bounds__(256) void scale_v1(short* __restrict__ Xbf,
                                                const float* __restrict__ colinv,
                                                float* __restrict__ aw) {
  const size_t gid = (size_t)blockIdx.x * 256 + threadIdx.x;
  const int rg = (int)(gid >> 7);
  const int ss = (int)(gid & 127);
  const int b = rg >> 10;
  const int gl = (ss & ~7) | ((ss & 7) ^ (rg & 7));   // logical granule
  const int h0 = gl * 8;
  short* p = Xbf + (size_t)rg * 1024 + ss * 8;
  const short8 v = *(const short8*)p;
  const float4 ci0 = *(const float4*)(colinv + (b << 10) + h0);
  const float4 ci1 = *(const float4*)(colinv + (b << 10) + h0 + 4);
  float f[8];
  f[0] = b2f((unsigned short)v[0]) * ci0.x; f[1] = b2f((unsigned short)v[1]) * ci0.y;
  f[2] = b2f((unsigned short)v[2]) * ci0.z; f[3] = b2f((unsigned short)v[3]) * ci0.w;
  f[4] = b2f((unsigned short)v[4]) * ci1.x; f[5] = b2f((unsigned short)v[5]) * ci1.y;
  f[6] = b2f((unsigned short)v[6]) * ci1.z; f[7] = b2f((unsigned short)v[7]) * ci1.w;
  float4 o0 = {f[0], f[1], f[2], f[3]};
  float4 o1 = {f[4], f[5], f[6], f[7]};
  *(float4*)(aw + (size_t)rg * 1024 + h0) = o0;
  *(float4*)(aw + (size_t)rg * 1024 + h0 + 4) = o1;
  short8 r;
#pragma unroll
  for (int j = 0; j < 8; ++j) r[j] = bfr(f[j]);
  *(short8*)p = r;
}

// ===========================================================================
// Fallback path (no workspace needed): R6/R7-proven kernels
// ===========================================================================
__global__ __launch_bounds__(256) void energy_mfma4(const short* __restrict__ enc_bf,
                                                    const short* __restrict__ W2_bf,
                                                    const float* __restrict__ c1,
                                                    float* __restrict__ X) {
  __shared__ __align__(16) short Ast[128 * 64];
  __shared__ __align__(16) short Bst[128 * 64];
  const int flat = blockIdx.x + (blockIdx.y << 3) + (blockIdx.z << 6);
  const int swz = (flat & 7) * 128 + (flat >> 3);
  const int b = swz >> 6;
  const int row0 = ((swz >> 3) & 7) * 128;
  const int col0 = (swz & 7) * 128;
  const int t = threadIdx.x;
  const int l = t & 63;
  const int w = t >> 6;
  const int wr = w >> 1, wc = w & 1;
  const int fr = l & 15, kg = l >> 4;

  const short* Abase = enc_bf + (size_t)b * SH + (size_t)(row0 + w * 32 + (l >> 3)) * 1024 + (l & 7) * 8;
  const short* Bbase = W2_bf + (size_t)(col0 + w * 32 + (l >> 3)) * 1024 + (l & 7) * 8;
  short* Alds = Ast + w * 2048;
  short* Blds = Bst + w * 2048;

  f32x4 acc[4][4] = {};

  for (int k0 = 0; k0 < 1024; k0 += 64) {
#pragma unroll
    for (int j = 0; j < 4; ++j) {
      GLD16(Abase + k0 + j * 8 * 1024, Alds + j * 512);
      GLD16(Bbase + k0 + j * 8 * 1024, Blds + j * 512);
    }
    __syncthreads();
#pragma unroll
    for (int kk = 0; kk < 2; ++kk) {
      short8 af[4], bf4[4];
#pragma unroll
      for (int m = 0; m < 4; ++m) {
        const int r = wr * 64 + m * 16 + fr;
        af[m] = *(const short8*)&Ast[r * 64 + (((kk * 4 + kg) ^ (r & 7)) << 3)];
      }
#pragma unroll
      for (int n = 0; n < 4; ++n) {
        const int r = wc * 64 + n * 16 + fr;
        bf4[n] = *(const short8*)&Bst[r * 64 + (((kk * 4 + kg) ^ (r & 7)) << 3)];
      }
#pragma unroll
      for (int m = 0; m < 4; ++m)
#pragma unroll
        for (int n = 0; n < 4; ++n)
          acc[m][n] = __builtin_amdgcn_mfma_f32_16x16x32_bf16(af[m], bf4[n], acc[m][n], 0, 0, 0);
    }
    __syncthreads();
  }

  float* Xb = X + (size_t)b * SH;
#pragma unroll
  for (int n = 0; n < 4; ++n) {
    const int col = col0 + wc * 64 + n * 16 + fr;
    const float c1v = c1[b * 1024 + col];
#pragma unroll
    for (int m = 0; m < 4; ++m) {
      const int r0 = row0 + wr * 64 + m * 16 + kg * 4;
#pragma unroll
      for (int r = 0; r < 4; ++r)
        Xb[(size_t)(r0 + r) * 1024 + col] = exptanh(acc[m][n][r] + c1v);
    }
  }
}

__global__ __launch_bounds__(256) void norm_kernel(float* __restrict__ X) {
  const int b = blockIdx.x >> 4;
  const int hg = blockIdx.x & 15;
  const int l = threadIdx.x & 63;
  const int sg = threadIdx.x >> 6;
  float* col = X + (size_t)b * SH + hg * 64 + l;
  const int s0 = sg * 256;
  float sum = 0.f;
#pragma unroll 8
  for (int s = s0; s < s0 + 256; ++s) sum += col[(size_t)s * 1024];
  __shared__ float red[4][64];
  red[sg][l] = sum;
  __syncthreads();
  const float inv = 1.f / (red[0][l] + red[1][l] + red[2][l] + red[3][l]);
#pragma unroll 8
  for (int s = s0; s < s0 + 256; ++s) col[(size_t)s * 1024] *= inv;
}

// self-contained fallback GEMM2 (raw fp32 inputs)
__global__ __launch_bounds__(256) void context_mfma(const float* __restrict__ aw,
                                                    const float* __restrict__ enc,
                                                    float* __restrict__ ctx) {
  __shared__ __align__(16) short Ast[128 * 32];
  __shared__ __align__(16) short Bst[128 * 32];
  const int b = blockIdx.z;
  const int row0 = blockIdx.y * 128;
  const int col0 = blockIdx.x * 128;
  const int t = threadIdx.x;
  const int l = t & 63;
  const int w = t >> 6;
  const int wr = w >> 1, wc = w & 1;
  const int fr = l & 15, kg = l >> 4;

  const int sr = t >> 1;
  const int sc0 = (t & 1) * 2;
  const float* arow = aw + (size_t)b * SH + (size_t)(row0 + sr) * 1024;
  const int bcol = t & 127;
  const int kb0 = (t >> 7) * 2;
  const float* bcolp = enc + (size_t)b * SH + col0 + bcol;

  f32x4 acc[4][4] = {};

#define LSLOT(r, g) ((r) * 32 + (((g) ^ (((r) >> 1) & 3)) << 3))
  for (int k0 = 0; k0 < 1024; k0 += 32) {
    const float4 a0 = *(const float4*)(arow + k0 + sc0 * 8);
    const float4 a1 = *(const float4*)(arow + k0 + sc0 * 8 + 4);
    const float4 a2 = *(const float4*)(arow + k0 + sc0 * 8 + 8);
    const float4 a3 = *(const float4*)(arow + k0 + sc0 * 8 + 12);
    float bv[2][8];
#pragma unroll
    for (int j = 0; j < 2; ++j)
#pragma unroll
      for (int i = 0; i < 8; ++i)
        bv[j][i] = bcolp[(size_t)(k0 + (kb0 + j) * 8 + i) * 1024];
    __syncthreads();
    *(short8*)&Ast[LSLOT(sr, sc0)]     = cvt8(a0, a1);
    *(short8*)&Ast[LSLOT(sr, sc0 + 1)] = cvt8(a2, a3);
#pragma unroll
    for (int j = 0; j < 2; ++j) {
      short8 pk;
#pragma unroll
      for (int i = 0; i < 8; ++i) pk[i] = bfr(bv[j][i]);
      *(short8*)&Bst[LSLOT(bcol, kb0 + j)] = pk;
    }
    __syncthreads();
    short8 af[4], bf4[4];
#pragma unroll
    for (int m = 0; m < 4; ++m) {
      const int r = wr * 64 + m * 16 + fr;
      af[m] = *(const short8*)&Ast[LSLOT(r, kg)];
    }
#pragma unroll
    for (int n = 0; n < 4; ++n) {
      const int r = wc * 64 + n * 16 + fr;
      bf4[n] = *(const short8*)&Bst[LSLOT(r, kg)];
    }
#pragma unroll
    for (int m = 0; m < 4; ++m)
#pragma unroll
      for (int n = 0; n < 4; ++n)
        acc[m][n] = __builtin_amdgcn_mfma_f32_16x16x32_bf16(af[m], bf4[n], acc[m][n], 0, 0, 0);
  }

  float* Cb = ctx + (size_t)b * SH;
#pragma unroll
  for (int n = 0; n < 4; ++n) {
    const int col = col0 + wc * 64 + n * 16 + fr;
#pragma unroll
    for (int m = 0; m < 4; ++m) {
      const int r0 = row0 + wr * 64 + m * 16 + kg * 4;
#pragma unroll
      for (int r = 0; r < 4; ++r)
        Cb[(size_t)(r0 + r) * 1024 + col] = acc[m][n][r];
    }
  }
}

// ---------------------------------------------------------------------------
extern "C" void kernel_launch(void* const* d_in, const int* in_sizes, int n_in,
                              void* d_out, int out_size, void* d_ws, size_t ws_size,
                              hipStream_t stream) {
  (void)in_sizes; (void)n_in; (void)out_size;
  const float* ht     = (const float*)d_in[0];
  const float* enc    = (const float*)d_in[1];
  const float* W_attn = (const float*)d_in[2];
  const float* b_attn = (const float*)d_in[3];
  // d_in[4] (W_v) is dead code in the reference

  float* ctx = (float*)d_out;          // [B,S,H] context (written last)
  float* aw  = ctx + BSH;              // [B,S,H] attention_weights

  // scratch parked inside the (dead-until-GEMM2) ctx region:
  short* enc_bf = (short*)ctx;                         // 32 MB, bf16 swz8
  short* W2_bf  = (short*)(ctx + 8388608);             // 2 MB
  float* c1f    = ctx + 8912896;                       // 64 KB
  float* part   = c1f + 16384;                         // 8 x 64 KB partial sums
  float* colinv = part + 8 * 16384;                    // 64 KB

  const bool ws2 = ws_size >= ((size_t)64 << 20);      // encT + Xbf
  short* encT = (short*)d_ws;                          // 32 MB
  short* Xbf  = (short*)((char*)d_ws + ((size_t)32 << 20));  // 32 MB

  cvt_w2_kernel<<<512, 256, 0, stream>>>(W_attn, W2_bf);
  c1_kernel<<<Hn / 4, 256, 0, stream>>>(ht, W_attn, b_attn, c1f);

  if (ws2) {
    dim3 gt(16, 16, Bn);
    fused_cvt_kernel<<<gt, 256, 0, stream>>>(enc, enc_bf, encT);
    energy8<<<256, 512, 0, stream>>>(enc_bf, W2_bf, c1f, Xbf, part);
    rcp_kernel<<<64, 256, 0, stream>>>(part, colinv);
    scale_v1<<<8192, 256, 0, stream>>>(Xbf, colinv, aw);
    context8<<<256, 512, 0, stream>>>(Xbf, encT, ctx);
  } else {
    cvt_enc_kernel<<<8192, 256, 0, stream>>>(enc, enc_bf);
    dim3 g(8, 8, Bn);
    energy_mfma4<<<g, 256, 0, stream>>>(enc_bf, W2_bf, c1f, aw);
    norm_kernel<<<Bn * 16, 256, 0, stream>>>(aw);
    context_mfma<<<g, 256, 0, stream>>>(aw, enc, ctx);
  }
}

// Round 12
// 159.579 us; speedup vs baseline: 1.0803x; 1.0199x over previous
//
#include <hip/hip_runtime.h>
#include <math.h>

#define Bn 16
#define Sn 1024
#define Hn 1024
static const size_t SH = (size_t)Sn * Hn;          // 1,048,576
static const size_t BSH = (size_t)Bn * Sn * Hn;    // 16,777,216

typedef __attribute__((ext_vector_type(8))) short short8;
typedef __attribute__((ext_vector_type(4))) float f32x4;

// async global->LDS, 16B per lane; LDS dest is wave-uniform base + lane*16
#define GLD16(gp, lp) __builtin_amdgcn_global_load_lds( \
    (const __attribute__((address_space(1))) void*)(gp), \
    (__attribute__((address_space(3))) void*)(lp), 16, 0, 0)

// round-to-nearest-even fp32 -> bf16
__device__ __forceinline__ short bfr(float f) {
  union { float f; unsigned u; } v; v.f = f;
  unsigned r = (v.u + 0x7FFFu + ((v.u >> 16) & 1u)) >> 16;
  return (short)r;
}
__device__ __forceinline__ float b2f(unsigned short u) {
  union { unsigned u; float f; } v; v.u = (unsigned)u << 16; return v.f;
}
__device__ __forceinline__ short8 cvt8(float4 x, float4 y) {
  short8 r;
  r[0] = bfr(x.x); r[1] = bfr(x.y); r[2] = bfr(x.z); r[3] = bfr(x.w);
  r[4] = bfr(y.x); r[5] = bfr(y.y); r[6] = bfr(y.z); r[7] = bfr(y.w);
  return r;
}
// X = exp(tanh(x)) with fast rcp: tanh = 1 - 2/(e^{2x}+1)
__device__ __forceinline__ float exptanh(float x) {
  const float e = __expf(2.f * x);
  const float r = __builtin_amdgcn_rcpf(e + 1.f);
  return __expf(1.f - 2.f * r);
}

// 8-granule swizzle: storage slot of logical granule g in row `row` is
// g ^ (row&7) within each 8-granule (64-element) k-block. Involution.
__device__ __forceinline__ int swz8(int row, int g) {
  return (g & ~7) | ((g & 7) ^ (row & 7));
}

// ---------------------------------------------------------------------------
// fused_cvt: enc[b][s][h] -> enc_bf (bf16, swz8 rows)  AND  encT (swz8 rows)
// ---------------------------------------------------------------------------
__global__ __launch_bounds__(256) void fused_cvt_kernel(const float* __restrict__ enc,
                                                        short* __restrict__ enc_bf,
                                                        short* __restrict__ encT) {
  __shared__ float tile[64][65];
  const int b = blockIdx.z;
  const int s0 = blockIdx.y * 64, h0 = blockIdx.x * 64;
  const int t = threadIdx.x;
  const int tr = t >> 4, tc = t & 15;
  const float* src = enc + (size_t)b * SH;
#pragma unroll
  for (int i = 0; i < 4; ++i) {
    const int s = i * 16 + tr;
    const float4 v = *(const float4*)(src + (size_t)(s0 + s) * 1024 + h0 + tc * 4);
    tile[s][tc * 4 + 0] = v.x; tile[s][tc * 4 + 1] = v.y;
    tile[s][tc * 4 + 2] = v.z; tile[s][tc * 4 + 3] = v.w;
  }
  __syncthreads();
  {
    const int rloc = t >> 2;
    const int rg = b * 1024 + s0 + rloc;
#pragma unroll
    for (int jj = 0; jj < 2; ++jj) {
      const int jloc = (t & 3) * 2 + jj;
      const int slot = jloc ^ (rg & 7);
      const float4 x = *(const float4*)&tile[rloc][jloc * 8];
      const float4 y = *(const float4*)&tile[rloc][jloc * 8 + 4];
      *(short8*)(enc_bf + (size_t)rg * 1024 + h0 + slot * 8) = cvt8(x, y);
    }
  }
  {
    const int hr = t >> 2, cs = t & 3;
    const int h = h0 + hr;
#pragma unroll
    for (int blk = 0; blk < 2; ++blk) {
      const int sg = blk * 4 + cs;
      const int gl = (s0 >> 3) + sg;
      const int gst = swz8(h, gl);
      short8 pk;
#pragma unroll
      for (int j = 0; j < 8; ++j) pk[j] = bfr(tile[sg * 8 + j][hr]);
      *(short8*)(encT + (size_t)b * SH + (size_t)h * 1024 + gst * 8) = pk;
    }
  }
}

// ---------------------------------------------------------------------------
// cvt_enc (fallback): enc -> enc_bf, swz8
// ---------------------------------------------------------------------------
__global__ __launch_bounds__(256) void cvt_enc_kernel(const float* __restrict__ enc,
                                                      short* __restrict__ enc_bf) {
  const int g = blockIdx.x * 256 + threadIdx.x;
  const int row = g >> 7;
  const int cs = g & 127;
  const float4 x = *(const float4*)(enc + (size_t)row * 1024 + cs * 8);
  const float4 y = *(const float4*)(enc + (size_t)row * 1024 + cs * 8 + 4);
  *(short8*)(enc_bf + (size_t)row * 1024 + swz8(row, cs) * 8) = cvt8(x, y);
}

// ---------------------------------------------------------------------------
// c1w2: c1[b,h] = ht[b,:] . W_attn[h, 0:H] + b_attn[h]   (grid Hn/4)
//       + fused W2 conversion: W2_bf[h] = bf16(W_attn[h][1024:2048]), swz8
// ---------------------------------------------------------------------------
__global__ __launch_bounds__(256) void c1w2_kernel(const float* __restrict__ ht,
                                                   const float* __restrict__ W_attn,
                                                   const float* __restrict__ b_attn,
                                                   float* __restrict__ c1,
                                                   short* __restrict__ W2_bf) {
  __shared__ float hts[16384];
  const int t = threadIdx.x;
#pragma unroll
  for (int i = 0; i < 16; ++i)
    *(float4*)&hts[i * 1024 + t * 4] = *(const float4*)&ht[i * 1024 + t * 4];
  __syncthreads();
  const int h = blockIdx.x * 4 + (t >> 6);
  const int lane = t & 63;
  const float* w = W_attn + (size_t)h * 2048;
  // fused W2 conversion: lane handles granules 2*lane, 2*lane+1 of row h
  {
    const float* w2 = w + 1024;
#pragma unroll
    for (int j = 0; j < 2; ++j) {
      const int cs = lane * 2 + j;
      const float4 x = *(const float4*)(w2 + cs * 8);
      const float4 y = *(const float4*)(w2 + cs * 8 + 4);
      *(short8*)(W2_bf + (size_t)h * 1024 + swz8(h, cs) * 8) = cvt8(x, y);
    }
  }
  float s[16];
#pragma unroll
  for (int b = 0; b < 16; ++b) s[b] = 0.f;
  for (int k = lane; k < 1024; k += 64) {
    const float wv = w[k];
#pragma unroll
    for (int b = 0; b < 16; ++b) s[b] = fmaf(wv, hts[b * 1024 + k], s[b]);
  }
#pragma unroll
  for (int b = 0; b < 16; ++b) {
    float v = s[b];
#pragma unroll
    for (int off = 32; off; off >>= 1) v += __shfl_down(v, off, 64);
    if (lane == 0) c1[b * 1024 + h] = v + b_attn[h];
  }
}

// ===========================================================================
// 8-phase 256x256 GEMM template (m201-style, plain HIP).
// 512 thr = 8 waves (2 wr x 4 wc); BK=64; LDS 128KB = 2 dbuf x (A 32K + B 32K).
// Stage schedule (tile kt): p0->B1(kt+1), p1->A1(kt+1), p2->A0(kt+2),
// p3->B0(kt+2). vmcnt(4) once per tile; raw barriers keep stages in flight.
// Global operands swz8-pre-swizzled; GLD16 writes LDS linearly; reads XOR.
// PROVEN race-free across graph replays (R9/R11).
// ===========================================================================
#define STAGE_A(kt, mh) do {                                              \
  const int p_ = (kt) & 1;                                                \
  _Pragma("unroll") for (int ld_ = 0; ld_ < 2; ++ld_) {                   \
    const int rl_ = (ld_ * 8 + wid) * 8 + (l >> 3);                       \
    GLD16(Ag + (size_t)((rl_ >> 6) * 128 + (mh) * 64 + (rl_ & 63)) * 1024 \
             + (kt) * 64 + (l & 7) * 8,                                   \
          &lds[p_ * 32768 + (mh) * 8192 + (ld_ * 8 + wid) * 512]);        \
  } } while (0)

#define STAGE_B(kt, nh) do {                                              \
  const int p_ = (kt) & 1;                                                \
  _Pragma("unroll") for (int ld_ = 0; ld_ < 2; ++ld_) {                   \
    const int rl_ = (ld_ * 8 + wid) * 8 + (l >> 3);                       \
    GLD16(Bg + (size_t)((rl_ >> 5) * 64 + (nh) * 32 + (rl_ & 31)) * 1024  \
             + (kt) * 64 + (l & 7) * 8,                                   \
          &lds[16384 + p_ * 32768 + (nh) * 8192 + (ld_ * 8 + wid) * 512]); \
  } } while (0)

#define PHASE(mh, nh, ...) do {                                           \
  if ((nh) == 0) {                                                        \
    _Pragma("unroll") for (int mi = 0; mi < 4; ++mi)                      \
      _Pragma("unroll") for (int ks = 0; ks < 2; ++ks)                    \
        afr[mi][ks] = *(const short8*)&lds[ab + (mh) * 8192               \
            + (wr * 64 + mi * 16 + fr) * 64                               \
            + (((ks * 4 + kg) ^ (fr & 7)) << 3)];                         \
  }                                                                       \
  _Pragma("unroll") for (int ni = 0; ni < 2; ++ni)                        \
    _Pragma("unroll") for (int ks = 0; ks < 2; ++ks)                      \
      bfrg[ni][ks] = *(const short8*)&lds[bb + (nh) * 8192                \
          + (wc * 32 + ni * 16 + fr) * 64                                 \
          + (((ks * 4 + kg) ^ (fr & 7)) << 3)];                           \
  __VA_ARGS__;                                                            \
  __builtin_amdgcn_s_barrier();                                           \
  __builtin_amdgcn_s_setprio(1);                                          \
  _Pragma("unroll") for (int mi = 0; mi < 4; ++mi)                        \
    _Pragma("unroll") for (int ni = 0; ni < 2; ++ni)                      \
      _Pragma("unroll") for (int ks = 0; ks < 2; ++ks)                    \
        acc[(mh) * 4 + mi][(nh) * 2 + ni] =                               \
            __builtin_amdgcn_mfma_f32_16x16x32_bf16(afr[mi][ks],          \
                bfrg[ni][ks], acc[(mh) * 4 + mi][(nh) * 2 + ni], 0, 0, 0); \
  __builtin_amdgcn_s_setprio(0);                                          \
} while (0)

#define KLOOP_8PHASE()                                                    \
  STAGE_A(0, 0); STAGE_B(0, 0); STAGE_B(0, 1); STAGE_A(0, 1);             \
  STAGE_A(1, 0); STAGE_B(1, 0);                                           \
  asm volatile("s_waitcnt vmcnt(4)" ::: "memory");                        \
  __builtin_amdgcn_s_barrier();                                           \
  _Pragma("unroll 2") for (int kt = 0; kt < 16; ++kt) {                   \
    const int ab = (kt & 1) * 32768;                                      \
    const int bb = 16384 + (kt & 1) * 32768;                              \
    PHASE(0, 0, if (kt < 15) STAGE_B(kt + 1, 1));                         \
    __builtin_amdgcn_s_barrier();                                         \
    PHASE(0, 1, if (kt < 15) STAGE_A(kt + 1, 1));                         \
    __builtin_amdgcn_s_barrier();                                         \
    PHASE(1, 0, if (kt < 14) STAGE_A(kt + 2, 0));                         \
    __builtin_amdgcn_s_barrier();                                         \
    PHASE(1, 1, if (kt < 14) STAGE_B(kt + 2, 0));                         \
    if (kt < 14) asm volatile("s_waitcnt vmcnt(4)" ::: "memory");         \
    else         asm volatile("s_waitcnt vmcnt(0)" ::: "memory");         \
    __builtin_amdgcn_s_barrier();                                         \
  }

// ---------------------------------------------------------------------------
// GEMM1 (8-phase): Xbf = bf16(exp(tanh(enc_bf . W2_bf^T + c1))) [swz8 layout]
// + per-(row_blk,wr) partial column sums (no atomics, no init needed).
// Epilogue obuf uses ROTATION layout (slot = (g+row)&31): rows 4 apart land
// on alternating bank-groups -> <=2-way aliasing (free) vs old 8-way.
// ---------------------------------------------------------------------------
__global__ __launch_bounds__(512) void energy8(const short* __restrict__ enc_bf,
                                               const short* __restrict__ W2_bf,
                                               const float* __restrict__ c1,
                                               short* __restrict__ Xbf,
                                               float* __restrict__ part) {
  __shared__ __align__(16) short lds[65536];   // 128 KB
  const int flat = blockIdx.x;
  const int id = (flat & 7) * 32 + (flat >> 3);   // XCD-chunked (256 = 8*32)
  const int b = id >> 4;
  const int rb = (id >> 2) & 3;
  const int row0 = rb * 256;
  const int col0 = (id & 3) * 256;
  const int t = threadIdx.x;
  const int wid = t >> 6, l = t & 63;
  const int wr = wid >> 2, wc = wid & 3;
  const int fr = l & 15, kg = l >> 4;

  const short* Ag = enc_bf + (size_t)b * SH + (size_t)row0 * 1024;
  const short* Bg = W2_bf + (size_t)col0 * 1024;

  f32x4 acc[8][4] = {};
  short8 afr[4][2], bfrg[2][2];

  KLOOP_8PHASE();
  __syncthreads();   // full fence before LDS reuse

  // epilogue: X = exp(tanh(acc+c1)); obuf bf16 (rotation layout);
  // partial colsum plane p = rb*2+wr (each slot written exactly once).
  unsigned short* obuf = (unsigned short*)lds;   // 256x256 ushort = 128 KB
  float* pplane = part + (size_t)(rb * 2 + wr) * 16384 + b * 1024 + col0;
#pragma unroll
  for (int n = 0; n < 4; ++n) {
    const int col_loc = wc * 64 + n * 16 + fr;
    const float c1v = c1[b * 1024 + col0 + col_loc];
    float csum = 0.f;
#pragma unroll
    for (int m = 0; m < 8; ++m) {
#pragma unroll
      for (int r = 0; r < 4; ++r) {
        const int row_loc = wr * 128 + m * 16 + kg * 4 + r;
        const float X = exptanh(acc[m][n][r] + c1v);
        csum += X;
        const int g = col_loc >> 3;
        const int s2 = (g + row_loc) & 31;       // rotation: bank-spread
        obuf[row_loc * 256 + s2 * 8 + (col_loc & 7)] = (unsigned short)bfr(X);
      }
    }
    csum += __shfl_xor(csum, 16);
    csum += __shfl_xor(csum, 32);
    if (l < 16) pplane[col_loc] = csum;
  }
  __syncthreads();
  // copy-out: global slot q holds logical granule gq = (q&~7)|((q&7)^(row&7))
  // which lives at LDS slot (gq+row)&31.
  const int orow = t >> 1;
  short* gd = Xbf + (size_t)b * SH + (size_t)(row0 + orow) * 1024 + col0;
#pragma unroll
  for (int j = 0; j < 16; ++j) {
    const int q = (t & 1) * 16 + j;
    const int gq = (q & ~7) | ((q & 7) ^ (orow & 7));
    const int ls = (gq + orow) & 31;
    *(short8*)(gd + q * 8) = *(short8*)&obuf[orow * 256 + ls * 8];
  }
}

// ---------------------------------------------------------------------------
// GEMM2 (8-phase): ctx = awbf . encT^T
// ---------------------------------------------------------------------------
__global__ __launch_bounds__(512) void context8(const short* __restrict__ awbf,
                                                const short* __restrict__ encT,
                                                float* __restrict__ ctx) {
  __shared__ __align__(16) short lds[65536];
  const int flat = blockIdx.x;
  const int id = (flat & 7) * 32 + (flat >> 3);
  const int b = id >> 4;
  const int row0 = ((id >> 2) & 3) * 256;
  const int col0 = (id & 3) * 256;
  const int t = threadIdx.x;
  const int wid = t >> 6, l = t & 63;
  const int wr = wid >> 2, wc = wid & 3;
  const int fr = l & 15, kg = l >> 4;

  const short* Ag = awbf + (size_t)b * SH + (size_t)row0 * 1024;
  const short* Bg = encT + (size_t)b * SH + (size_t)col0 * 1024;

  f32x4 acc[8][4] = {};
  short8 afr[4][2], bfrg[2][2];

  KLOOP_8PHASE();

  float* Cb = ctx + (size_t)b * SH;
#pragma unroll
  for (int n = 0; n < 4; ++n) {
    const int col = col0 + wc * 64 + n * 16 + fr;
#pragma unroll
    for (int m = 0; m < 8; ++m) {
#pragma unroll
      for (int r = 0; r < 4; ++r)
        Cb[(size_t)(row0 + wr * 128 + m * 16 + kg * 4 + r) * 1024 + col] = acc[m][n][r];
    }
  }
}

// ---------------------------------------------------------------------------
// rcp: colinv[i] = 1 / sum_p part[p][i]   (8 planes; 64 blocks)
// ---------------------------------------------------------------------------
__global__ __launch_bounds__(256) void rcp_kernel(const float* __restrict__ part,
                                                  float* __restrict__ ci) {
  const int i = blockIdx.x * 256 + threadIdx.x;
  float s = 0.f;
#pragma unroll
  for (int p = 0; p < 8; ++p) s += part[p * 16384 + i];
  ci[i] = 1.0f / s;
}

// ---------------------------------------------------------------------------
// scale: awbf = bf16(Xbf * colinv) in-place (swz8, same slot), aw fp32 out
// ---------------------------------------------------------------------------
__global__ __launch_bounds__(256) void scale_v1(short* __restrict__ Xbf,
                                                const float* __restrict__ colinv,
                                                float* __restrict__ aw) {
  const size_t gid = (size_t)blockIdx.x * 256 + threadIdx.x;
  const int rg = (int)(gid >> 7);
  const int ss = (int)(gid & 127);
  const int b = rg >> 10;
  const int gl = (ss & ~7) | ((ss & 7) ^ (rg & 7));   // logical granule
  const int h0 = gl * 8;
  short* p = Xbf + (size_t)rg * 1024 + ss * 8;
  const short8 v = *(const short8*)p;
  const float4 ci0 = *(const float4*)(colinv + (b << 10) + h0);
  const float4 ci1 = *(const float4*)(colinv + (b << 10) + h0 + 4);
  float f[8];
  f[0] = b2f((unsigned short)v[0]) * ci0.x; f[1] = b2f((unsigned short)v[1]) * ci0.y;
  f[2] = b2f((unsigned short)v[2]) * ci0.z; f[3] = b2f((unsigned short)v[3]) * ci0.w;
  f[4] = b2f((unsigned short)v[4]) * ci1.x; f[5] = b2f((unsigned short)v[5]) * ci1.y;
  f[6] = b2f((unsigned short)v[6]) * ci1.z; f[7] = b2f((unsigned short)v[7]) * ci1.w;
  float4 o0 = {f[0], f[1], f[2], f[3]};
  float4 o1 = {f[4], f[5], f[6], f[7]};
  *(float4*)(aw + (size_t)rg * 1024 + h0) = o0;
  *(float4*)(aw + (size_t)rg * 1024 + h0 + 4) = o1;
  short8 r;
#pragma unroll
  for (int j = 0; j < 8; ++j) r[j] = bfr(f[j]);
  *(short8*)p = r;
}

// ===========================================================================
// Fallback path (no workspace needed): R6/R7-proven kernels
// ===========================================================================
__global__ __launch_bounds__(256) void energy_mfma4(const short* __restrict__ enc_bf,
                                                    const short* __restrict__ W2_bf,
                                                    const float* __restrict__ c1,
                                                    float* __restrict__ X) {
  __shared__ __align__(16) short Ast[128 * 64];
  __shared__ __align__(16) short Bst[128 * 64];
  const int flat = blockIdx.x + (blockIdx.y << 3) + (blockIdx.z << 6);
  const int swz = (flat & 7) * 128 + (flat >> 3);
  const int b = swz >> 6;
  const int row0 = ((swz >> 3) & 7) * 128;
  const int col0 = (swz & 7) * 128;
  const int t = threadIdx.x;
  const int l = t & 63;
  const int w = t >> 6;
  const int wr = w >> 1, wc = w & 1;
  const int fr = l & 15, kg = l >> 4;

  const short* Abase = enc_bf + (size_t)b * SH + (size_t)(row0 + w * 32 + (l >> 3)) * 1024 + (l & 7) * 8;
  const short* Bbase = W2_bf + (size_t)(col0 + w * 32 + (l >> 3)) * 1024 + (l & 7) * 8;
  short* Alds = Ast + w * 2048;
  short* Blds = Bst + w * 2048;

  f32x4 acc[4][4] = {};

  for (int k0 = 0; k0 < 1024; k0 += 64) {
#pragma unroll
    for (int j = 0; j < 4; ++j) {
      GLD16(Abase + k0 + j * 8 * 1024, Alds + j * 512);
      GLD16(Bbase + k0 + j * 8 * 1024, Blds + j * 512);
    }
    __syncthreads();
#pragma unroll
    for (int kk = 0; kk < 2; ++kk) {
      short8 af[4], bf4[4];
#pragma unroll
      for (int m = 0; m < 4; ++m) {
        const int r = wr * 64 + m * 16 + fr;
        af[m] = *(const short8*)&Ast[r * 64 + (((kk * 4 + kg) ^ (r & 7)) << 3)];
      }
#pragma unroll
      for (int n = 0; n < 4; ++n) {
        const int r = wc * 64 + n * 16 + fr;
        bf4[n] = *(const short8*)&Bst[r * 64 + (((kk * 4 + kg) ^ (r & 7)) << 3)];
      }
#pragma unroll
      for (int m = 0; m < 4; ++m)
#pragma unroll
        for (int n = 0; n < 4; ++n)
          acc[m][n] = __builtin_amdgcn_mfma_f32_16x16x32_bf16(af[m], bf4[n], acc[m][n], 0, 0, 0);
    }
    __syncthreads();
  }

  float* Xb = X + (size_t)b * SH;
#pragma unroll
  for (int n = 0; n < 4; ++n) {
    const int col = col0 + wc * 64 + n * 16 + fr;
    const float c1v = c1[b * 1024 + col];
#pragma unroll
    for (int m = 0; m < 4; ++m) {
      const int r0 = row0 + wr * 64 + m * 16 + kg * 4;
#pragma unroll
      for (int r = 0; r < 4; ++r)
        Xb[(size_t)(r0 + r) * 1024 + col] = exptanh(acc[m][n][r] + c1v);
    }
  }
}

__global__ __launch_bounds__(256) void norm_kernel(float* __restrict__ X) {
  const int b = blockIdx.x >> 4;
  const int hg = blockIdx.x & 15;
  const int l = threadIdx.x & 63;
  const int sg = threadIdx.x >> 6;
  float* col = X + (size_t)b * SH + hg * 64 + l;
  const int s0 = sg * 256;
  float sum = 0.f;
#pragma unroll 8
  for (int s = s0; s < s0 + 256; ++s) sum += col[(size_t)s * 1024];
  __shared__ float red[4][64];
  red[sg][l] = sum;
  __syncthreads();
  const float inv = 1.f / (red[0][l] + red[1][l] + red[2][l] + red[3][l]);
#pragma unroll 8
  for (int s = s0; s < s0 + 256; ++s) col[(size_t)s * 1024] *= inv;
}

// self-contained fallback GEMM2 (raw fp32 inputs)
__global__ __launch_bounds__(256) void context_mfma(const float* __restrict__ aw,
                                                    const float* __restrict__ enc,
                                                    float* __restrict__ ctx) {
  __shared__ __align__(16) short Ast[128 * 32];
  __shared__ __align__(16) short Bst[128 * 32];
  const int b = blockIdx.z;
  const int row0 = blockIdx.y * 128;
  const int col0 = blockIdx.x * 128;
  const int t = threadIdx.x;
  const int l = t & 63;
  const int w = t >> 6;
  const int wr = w >> 1, wc = w & 1;
  const int fr = l & 15, kg = l >> 4;

  const int sr = t >> 1;
  const int sc0 = (t & 1) * 2;
  const float* arow = aw + (size_t)b * SH + (size_t)(row0 + sr) * 1024;
  const int bcol = t & 127;
  const int kb0 = (t >> 7) * 2;
  const float* bcolp = enc + (size_t)b * SH + col0 + bcol;

  f32x4 acc[4][4] = {};

#define LSLOT(r, g) ((r) * 32 + (((g) ^ (((r) >> 1) & 3)) << 3))
  for (int k0 = 0; k0 < 1024; k0 += 32) {
    const float4 a0 = *(const float4*)(arow + k0 + sc0 * 8);
    const float4 a1 = *(const float4*)(arow + k0 + sc0 * 8 + 4);
    const float4 a2 = *(const float4*)(arow + k0 + sc0 * 8 + 8);
    const float4 a3 = *(const float4*)(arow + k0 + sc0 * 8 + 12);
    float bv[2][8];
#pragma unroll
    for (int j = 0; j < 2; ++j)
#pragma unroll
      for (int i = 0; i < 8; ++i)
        bv[j][i] = bcolp[(size_t)(k0 + (kb0 + j) * 8 + i) * 1024];
    __syncthreads();
    *(short8*)&Ast[LSLOT(sr, sc0)]     = cvt8(a0, a1);
    *(short8*)&Ast[LSLOT(sr, sc0 + 1)] = cvt8(a2, a3);
#pragma unroll
    for (int j = 0; j < 2; ++j) {
      short8 pk;
#pragma unroll
      for (int i = 0; i < 8; ++i) pk[i] = bfr(bv[j][i]);
      *(short8*)&Bst[LSLOT(bcol, kb0 + j)] = pk;
    }
    __syncthreads();
    short8 af[4], bf4[4];
#pragma unroll
    for (int m = 0; m < 4; ++m) {
      const int r = wr * 64 + m * 16 + fr;
      af[m] = *(const short8*)&Ast[LSLOT(r, kg)];
    }
#pragma unroll
    for (int n = 0; n < 4; ++n) {
      const int r = wc * 64 + n * 16 + fr;
      bf4[n] = *(const short8*)&Bst[LSLOT(r, kg)];
    }
#pragma unroll
    for (int m = 0; m < 4; ++m)
#pragma unroll
      for (int n = 0; n < 4; ++n)
        acc[m][n] = __builtin_amdgcn_mfma_f32_16x16x32_bf16(af[m], bf4[n], acc[m][n], 0, 0, 0);
  }

  float* Cb = ctx + (size_t)b * SH;
#pragma unroll
  for (int n = 0; n < 4; ++n) {
    const int col = col0 + wc * 64 + n * 16 + fr;
#pragma unroll
    for (int m = 0; m < 4; ++m) {
      const int r0 = row0 + wr * 64 + m * 16 + kg * 4;
#pragma unroll
      for (int r = 0; r < 4; ++r)
        Cb[(size_t)(r0 + r) * 1024 + col] = acc[m][n][r];
    }
  }
}

// ---------------------------------------------------------------------------
extern "C" void kernel_launch(void* const* d_in, const int* in_sizes, int n_in,
                              void* d_out, int out_size, void* d_ws, size_t ws_size,
                              hipStream_t stream) {
  (void)in_sizes; (void)n_in; (void)out_size;
  const float* ht     = (const float*)d_in[0];
  const float* enc    = (const float*)d_in[1];
  const float* W_attn = (const float*)d_in[2];
  const float* b_attn = (const float*)d_in[3];
  // d_in[4] (W_v) is dead code in the reference

  float* ctx = (float*)d_out;          // [B,S,H] context (written last)
  float* aw  = ctx + BSH;              // [B,S,H] attention_weights

  // scratch parked inside the (dead-until-GEMM2) ctx region:
  short* enc_bf = (short*)ctx;                         // 32 MB, bf16 swz8
  short* W2_bf  = (short*)(ctx + 8388608);             // 2 MB
  float* c1f    = ctx + 8912896;                       // 64 KB
  float* part   = c1f + 16384;                         // 8 x 64 KB partial sums
  float* colinv = part + 8 * 16384;                    // 64 KB

  const bool ws2 = ws_size >= ((size_t)64 << 20);      // encT + Xbf
  short* encT = (short*)d_ws;                          // 32 MB
  short* Xbf  = (short*)((char*)d_ws + ((size_t)32 << 20));  // 32 MB

  c1w2_kernel<<<Hn / 4, 256, 0, stream>>>(ht, W_attn, b_attn, c1f, W2_bf);

  if (ws2) {
    dim3 gt(16, 16, Bn);
    fused_cvt_kernel<<<gt, 256, 0, stream>>>(enc, enc_bf, encT);
    energy8<<<256, 512, 0, stream>>>(enc_bf, W2_bf, c1f, Xbf, part);
    rcp_kernel<<<64, 256, 0, stream>>>(part, colinv);
    scale_v1<<<8192, 256, 0, stream>>>(Xbf, colinv, aw);
    context8<<<256, 512, 0, stream>>>(Xbf, encT, ctx);
  } else {
    cvt_enc_kernel<<<8192, 256, 0, stream>>>(enc, enc_bf);
    dim3 g(8, 8, Bn);
    energy_mfma4<<<g, 256, 0, stream>>>(enc_bf, W2_bf, c1f, aw);
    norm_kernel<<<Bn * 16, 256, 0, stream>>>(aw);
    context_mfma<<<g, 256, 0, stream>>>(aw, enc, ctx);
  }
}

// Round 13
// 155.795 us; speedup vs baseline: 1.1066x; 1.0243x over previous
//
#include <hip/hip_runtime.h>
#include <math.h>

#define Bn 16
#define Sn 1024
#define Hn 1024
static const size_t SH = (size_t)Sn * Hn;          // 1,048,576
static const size_t BSH = (size_t)Bn * Sn * Hn;    // 16,777,216

typedef __attribute__((ext_vector_type(8))) short short8;
typedef __attribute__((ext_vector_type(4))) float f32x4;

// async global->LDS, 16B per lane; LDS dest is wave-uniform base + lane*16
#define GLD16(gp, lp) __builtin_amdgcn_global_load_lds( \
    (const __attribute__((address_space(1))) void*)(gp), \
    (__attribute__((address_space(3))) void*)(lp), 16, 0, 0)

// round-to-nearest-even fp32 -> bf16
__device__ __forceinline__ short bfr(float f) {
  union { float f; unsigned u; } v; v.f = f;
  unsigned r = (v.u + 0x7FFFu + ((v.u >> 16) & 1u)) >> 16;
  return (short)r;
}
__device__ __forceinline__ float b2f(unsigned short u) {
  union { unsigned u; float f; } v; v.u = (unsigned)u << 16; return v.f;
}
__device__ __forceinline__ short8 cvt8(float4 x, float4 y) {
  short8 r;
  r[0] = bfr(x.x); r[1] = bfr(x.y); r[2] = bfr(x.z); r[3] = bfr(x.w);
  r[4] = bfr(y.x); r[5] = bfr(y.y); r[6] = bfr(y.z); r[7] = bfr(y.w);
  return r;
}
// X = exp(tanh(x)) with fast rcp: tanh = 1 - 2/(e^{2x}+1)
__device__ __forceinline__ float exptanh(float x) {
  const float e = __expf(2.f * x);
  const float r = __builtin_amdgcn_rcpf(e + 1.f);
  return __expf(1.f - 2.f * r);
}

// 8-granule swizzle: storage slot of logical granule g in row `row` is
// g ^ (row&7) within each 8-granule (64-element) k-block. Involution.
__device__ __forceinline__ int swz8(int row, int g) {
  return (g & ~7) | ((g & 7) ^ (row & 7));
}

// ---------------------------------------------------------------------------
// prep: ONE launch doing both
//   blocks [0,4096):   fused_cvt — enc -> enc_bf (swz8) AND encT (swz8)
//   blocks [4096,4352): c1 + W2 cvt — c1[b,h], W2_bf[h] (swz8)
// c1 part uses 16KB k-chunked ht staging so the merged kernel keeps the
// cvt part's occupancy (union'd 16.6KB LDS).
// ---------------------------------------------------------------------------
__global__ __launch_bounds__(256) void prep_kernel(const float* __restrict__ enc,
                                                   const float* __restrict__ ht,
                                                   const float* __restrict__ W_attn,
                                                   const float* __restrict__ b_attn,
                                                   short* __restrict__ enc_bf,
                                                   short* __restrict__ encT,
                                                   float* __restrict__ c1,
                                                   short* __restrict__ W2_bf) {
  __shared__ float smem[4160];   // 16.6 KB, union: cvt tile / c1 ht-chunk
  const int blk = blockIdx.x;
  const int t = threadIdx.x;

  if (blk < 4096) {
    // ---- fused_cvt tile ----
    float (*tile)[65] = (float(*)[65])smem;
    const int b = blk >> 8;
    const int s0 = ((blk >> 4) & 15) * 64, h0 = (blk & 15) * 64;
    const int tr = t >> 4, tc = t & 15;
    const float* src = enc + (size_t)b * SH;
#pragma unroll
    for (int i = 0; i < 4; ++i) {
      const int s = i * 16 + tr;
      const float4 v = *(const float4*)(src + (size_t)(s0 + s) * 1024 + h0 + tc * 4);
      tile[s][tc * 4 + 0] = v.x; tile[s][tc * 4 + 1] = v.y;
      tile[s][tc * 4 + 2] = v.z; tile[s][tc * 4 + 3] = v.w;
    }
    __syncthreads();
    {
      const int rloc = t >> 2;
      const int rg = b * 1024 + s0 + rloc;
#pragma unroll
      for (int jj = 0; jj < 2; ++jj) {
        const int jloc = (t & 3) * 2 + jj;
        const int slot = jloc ^ (rg & 7);
        const float4 x = *(const float4*)&tile[rloc][jloc * 8];
        const float4 y = *(const float4*)&tile[rloc][jloc * 8 + 4];
        *(short8*)(enc_bf + (size_t)rg * 1024 + h0 + slot * 8) = cvt8(x, y);
      }
    }
    {
      const int hr = t >> 2, cs = t & 3;
      const int h = h0 + hr;
#pragma unroll
      for (int blkj = 0; blkj < 2; ++blkj) {
        const int sg = blkj * 4 + cs;
        const int gl = (s0 >> 3) + sg;
        const int gst = swz8(h, gl);
        short8 pk;
#pragma unroll
        for (int j = 0; j < 8; ++j) pk[j] = bfr(tile[sg * 8 + j][hr]);
        *(short8*)(encT + (size_t)b * SH + (size_t)h * 1024 + gst * 8) = pk;
      }
    }
  } else {
    // ---- c1 + W2 cvt (k-chunked ht staging, 16 KB) ----
    float* hts = smem;            // [16 batches][256 k] = 4096 floats
    const int bid = blk - 4096;
    const int h = bid * 4 + (t >> 6);
    const int lane = t & 63;
    const float* w = W_attn + (size_t)h * 2048;
    // fused W2 conversion: lane handles granules 2*lane, 2*lane+1 of row h
    {
      const float* w2 = w + 1024;
#pragma unroll
      for (int j = 0; j < 2; ++j) {
        const int cs = lane * 2 + j;
        const float4 x = *(const float4*)(w2 + cs * 8);
        const float4 y = *(const float4*)(w2 + cs * 8 + 4);
        *(short8*)(W2_bf + (size_t)h * 1024 + swz8(h, cs) * 8) = cvt8(x, y);
      }
    }
    float s[16];
#pragma unroll
    for (int b = 0; b < 16; ++b) s[b] = 0.f;
    for (int c = 0; c < 4; ++c) {
#pragma unroll
      for (int i = 0; i < 4; ++i) {
        const int idx = i * 1024 + t * 4;          // 0..4095
        const int b = idx >> 8, k = idx & 255;
        *(float4*)&hts[idx] = *(const float4*)&ht[b * 1024 + c * 256 + k];
      }
      __syncthreads();
#pragma unroll
      for (int ki = 0; ki < 4; ++ki) {
        const int k = ki * 64 + lane;
        const float wv = w[c * 256 + k];
#pragma unroll
        for (int b = 0; b < 16; ++b) s[b] = fmaf(wv, hts[b * 256 + k], s[b]);
      }
      __syncthreads();   // protect hts overwrite next chunk
    }
#pragma unroll
    for (int b = 0; b < 16; ++b) {
      float v = s[b];
#pragma unroll
      for (int off = 32; off; off >>= 1) v += __shfl_down(v, off, 64);
      if (lane == 0) c1[b * 1024 + h] = v + b_attn[h];
    }
  }
}

// ---------------------------------------------------------------------------
// cvt_enc (fallback): enc -> enc_bf, swz8
// ---------------------------------------------------------------------------
__global__ __launch_bounds__(256) void cvt_enc_kernel(const float* __restrict__ enc,
                                                      short* __restrict__ enc_bf) {
  const int g = blockIdx.x * 256 + threadIdx.x;
  const int row = g >> 7;
  const int cs = g & 127;
  const float4 x = *(const float4*)(enc + (size_t)row * 1024 + cs * 8);
  const float4 y = *(const float4*)(enc + (size_t)row * 1024 + cs * 8 + 4);
  *(short8*)(enc_bf + (size_t)row * 1024 + swz8(row, cs) * 8) = cvt8(x, y);
}

// ---------------------------------------------------------------------------
// c1w2 (fallback): c1[b,h] + W2 cvt, 64KB ht stage (standalone proven)
// ---------------------------------------------------------------------------
__global__ __launch_bounds__(256) void c1w2_kernel(const float* __restrict__ ht,
                                                   const float* __restrict__ W_attn,
                                                   const float* __restrict__ b_attn,
                                                   float* __restrict__ c1,
                                                   short* __restrict__ W2_bf) {
  __shared__ float hts[16384];
  const int t = threadIdx.x;
#pragma unroll
  for (int i = 0; i < 16; ++i)
    *(float4*)&hts[i * 1024 + t * 4] = *(const float4*)&ht[i * 1024 + t * 4];
  __syncthreads();
  const int h = blockIdx.x * 4 + (t >> 6);
  const int lane = t & 63;
  const float* w = W_attn + (size_t)h * 2048;
  {
    const float* w2 = w + 1024;
#pragma unroll
    for (int j = 0; j < 2; ++j) {
      const int cs = lane * 2 + j;
      const float4 x = *(const float4*)(w2 + cs * 8);
      const float4 y = *(const float4*)(w2 + cs * 8 + 4);
      *(short8*)(W2_bf + (size_t)h * 1024 + swz8(h, cs) * 8) = cvt8(x, y);
    }
  }
  float s[16];
#pragma unroll
  for (int b = 0; b < 16; ++b) s[b] = 0.f;
  for (int k = lane; k < 1024; k += 64) {
    const float wv = w[k];
#pragma unroll
    for (int b = 0; b < 16; ++b) s[b] = fmaf(wv, hts[b * 1024 + k], s[b]);
  }
#pragma unroll
  for (int b = 0; b < 16; ++b) {
    float v = s[b];
#pragma unroll
    for (int off = 32; off; off >>= 1) v += __shfl_down(v, off, 64);
    if (lane == 0) c1[b * 1024 + h] = v + b_attn[h];
  }
}

// ===========================================================================
// 8-phase 256x256 GEMM template (m201-style, plain HIP).
// 512 thr = 8 waves (2 wr x 4 wc); BK=64; LDS 128KB = 2 dbuf x (A 32K + B 32K).
// Stage schedule (tile kt): p0->B1(kt+1), p1->A1(kt+1), p2->A0(kt+2),
// p3->B0(kt+2). vmcnt(4) once per tile; raw barriers keep stages in flight.
// Global operands swz8-pre-swizzled; GLD16 writes LDS linearly; reads XOR.
// PROVEN race-free across graph replays (R9/R11/R12).
// ===========================================================================
#define STAGE_A(kt, mh) do {                                              \
  const int p_ = (kt) & 1;                                                \
  _Pragma("unroll") for (int ld_ = 0; ld_ < 2; ++ld_) {                   \
    const int rl_ = (ld_ * 8 + wid) * 8 + (l >> 3);                       \
    GLD16(Ag + (size_t)((rl_ >> 6) * 128 + (mh) * 64 + (rl_ & 63)) * 1024 \
             + (kt) * 64 + (l & 7) * 8,                                   \
          &lds[p_ * 32768 + (mh) * 8192 + (ld_ * 8 + wid) * 512]);        \
  } } while (0)

#define STAGE_B(kt, nh) do {                                              \
  const int p_ = (kt) & 1;                                                \
  _Pragma("unroll") for (int ld_ = 0; ld_ < 2; ++ld_) {                   \
    const int rl_ = (ld_ * 8 + wid) * 8 + (l >> 3);                       \
    GLD16(Bg + (size_t)((rl_ >> 5) * 64 + (nh) * 32 + (rl_ & 31)) * 1024  \
             + (kt) * 64 + (l & 7) * 8,                                   \
          &lds[16384 + p_ * 32768 + (nh) * 8192 + (ld_ * 8 + wid) * 512]); \
  } } while (0)

#define PHASE(mh, nh, ...) do {                                           \
  if ((nh) == 0) {                                                        \
    _Pragma("unroll") for (int mi = 0; mi < 4; ++mi)                      \
      _Pragma("unroll") for (int ks = 0; ks < 2; ++ks)                    \
        afr[mi][ks] = *(const short8*)&lds[ab + (mh) * 8192               \
            + (wr * 64 + mi * 16 + fr) * 64                               \
            + (((ks * 4 + kg) ^ (fr & 7)) << 3)];                         \
  }                                                                       \
  _Pragma("unroll") for (int ni = 0; ni < 2; ++ni)                        \
    _Pragma("unroll") for (int ks = 0; ks < 2; ++ks)                      \
      bfrg[ni][ks] = *(const short8*)&lds[bb + (nh) * 8192                \
          + (wc * 32 + ni * 16 + fr) * 64                                 \
          + (((ks * 4 + kg) ^ (fr & 7)) << 3)];                           \
  __VA_ARGS__;                                                            \
  __builtin_amdgcn_s_barrier();                                           \
  __builtin_amdgcn_s_setprio(1);                                          \
  _Pragma("unroll") for (int mi = 0; mi < 4; ++mi)                        \
    _Pragma("unroll") for (int ni = 0; ni < 2; ++ni)                      \
      _Pragma("unroll") for (int ks = 0; ks < 2; ++ks)                    \
        acc[(mh) * 4 + mi][(nh) * 2 + ni] =                               \
            __builtin_amdgcn_mfma_f32_16x16x32_bf16(afr[mi][ks],          \
                bfrg[ni][ks], acc[(mh) * 4 + mi][(nh) * 2 + ni], 0, 0, 0); \
  __builtin_amdgcn_s_setprio(0);                                          \
} while (0)

#define KLOOP_8PHASE()                                                    \
  STAGE_A(0, 0); STAGE_B(0, 0); STAGE_B(0, 1); STAGE_A(0, 1);             \
  STAGE_A(1, 0); STAGE_B(1, 0);                                           \
  asm volatile("s_waitcnt vmcnt(4)" ::: "memory");                        \
  __builtin_amdgcn_s_barrier();                                           \
  _Pragma("unroll 2") for (int kt = 0; kt < 16; ++kt) {                   \
    const int ab = (kt & 1) * 32768;                                      \
    const int bb = 16384 + (kt & 1) * 32768;                              \
    PHASE(0, 0, if (kt < 15) STAGE_B(kt + 1, 1));                         \
    __builtin_amdgcn_s_barrier();                                         \
    PHASE(0, 1, if (kt < 15) STAGE_A(kt + 1, 1));                         \
    __builtin_amdgcn_s_barrier();                                         \
    PHASE(1, 0, if (kt < 14) STAGE_A(kt + 2, 0));                         \
    __builtin_amdgcn_s_barrier();                                         \
    PHASE(1, 1, if (kt < 14) STAGE_B(kt + 2, 0));                         \
    if (kt < 14) asm volatile("s_waitcnt vmcnt(4)" ::: "memory");         \
    else         asm volatile("s_waitcnt vmcnt(0)" ::: "memory");         \
    __builtin_amdgcn_s_barrier();                                         \
  }

// ---------------------------------------------------------------------------
// GEMM1 (8-phase): Xbf = bf16(exp(tanh(enc_bf . W2_bf^T + c1))) [swz8 layout]
// + per-(row_blk,wr) partial column sums (no atomics, no init needed).
// Epilogue obuf uses ROTATION layout (slot = (g+row)&31): <=2-way aliasing.
// ---------------------------------------------------------------------------
__global__ __launch_bounds__(512) void energy8(const short* __restrict__ enc_bf,
                                               const short* __restrict__ W2_bf,
                                               const float* __restrict__ c1,
                                               short* __restrict__ Xbf,
                                               float* __restrict__ part) {
  __shared__ __align__(16) short lds[65536];   // 128 KB
  const int flat = blockIdx.x;
  const int id = (flat & 7) * 32 + (flat >> 3);   // XCD-chunked (256 = 8*32)
  const int b = id >> 4;
  const int rb = (id >> 2) & 3;
  const int row0 = rb * 256;
  const int col0 = (id & 3) * 256;
  const int t = threadIdx.x;
  const int wid = t >> 6, l = t & 63;
  const int wr = wid >> 2, wc = wid & 3;
  const int fr = l & 15, kg = l >> 4;

  const short* Ag = enc_bf + (size_t)b * SH + (size_t)row0 * 1024;
  const short* Bg = W2_bf + (size_t)col0 * 1024;

  f32x4 acc[8][4] = {};
  short8 afr[4][2], bfrg[2][2];

  KLOOP_8PHASE();
  __syncthreads();   // full fence before LDS reuse

  unsigned short* obuf = (unsigned short*)lds;   // 256x256 ushort = 128 KB
  float* pplane = part + (size_t)(rb * 2 + wr) * 16384 + b * 1024 + col0;
#pragma unroll
  for (int n = 0; n < 4; ++n) {
    const int col_loc = wc * 64 + n * 16 + fr;
    const float c1v = c1[b * 1024 + col0 + col_loc];
    float csum = 0.f;
#pragma unroll
    for (int m = 0; m < 8; ++m) {
#pragma unroll
      for (int r = 0; r < 4; ++r) {
        const int row_loc = wr * 128 + m * 16 + kg * 4 + r;
        const float X = exptanh(acc[m][n][r] + c1v);
        csum += X;
        const int g = col_loc >> 3;
        const int s2 = (g + row_loc) & 31;       // rotation: bank-spread
        obuf[row_loc * 256 + s2 * 8 + (col_loc & 7)] = (unsigned short)bfr(X);
      }
    }
    csum += __shfl_xor(csum, 16);
    csum += __shfl_xor(csum, 32);
    if (l < 16) pplane[col_loc] = csum;
  }
  __syncthreads();
  // copy-out: global slot q holds logical granule gq = (q&~7)|((q&7)^(row&7))
  // which lives at LDS slot (gq+row)&31.
  const int orow = t >> 1;
  short* gd = Xbf + (size_t)b * SH + (size_t)(row0 + orow) * 1024 + col0;
#pragma unroll
  for (int j = 0; j < 16; ++j) {
    const int q = (t & 1) * 16 + j;
    const int gq = (q & ~7) | ((q & 7) ^ (orow & 7));
    const int ls = (gq + orow) & 31;
    *(short8*)(gd + q * 8) = *(short8*)&obuf[orow * 256 + ls * 8];
  }
}

// ---------------------------------------------------------------------------
// GEMM2 (8-phase): ctx = awbf . encT^T
// ---------------------------------------------------------------------------
__global__ __launch_bounds__(512) void context8(const short* __restrict__ awbf,
                                                const short* __restrict__ encT,
                                                float* __restrict__ ctx) {
  __shared__ __align__(16) short lds[65536];
  const int flat = blockIdx.x;
  const int id = (flat & 7) * 32 + (flat >> 3);
  const int b = id >> 4;
  const int row0 = ((id >> 2) & 3) * 256;
  const int col0 = (id & 3) * 256;
  const int t = threadIdx.x;
  const int wid = t >> 6, l = t & 63;
  const int wr = wid >> 2, wc = wid & 3;
  const int fr = l & 15, kg = l >> 4;

  const short* Ag = awbf + (size_t)b * SH + (size_t)row0 * 1024;
  const short* Bg = encT + (size_t)b * SH + (size_t)col0 * 1024;

  f32x4 acc[8][4] = {};
  short8 afr[4][2], bfrg[2][2];

  KLOOP_8PHASE();

  float* Cb = ctx + (size_t)b * SH;
#pragma unroll
  for (int n = 0; n < 4; ++n) {
    const int col = col0 + wc * 64 + n * 16 + fr;
#pragma unroll
    for (int m = 0; m < 8; ++m) {
#pragma unroll
      for (int r = 0; r < 4; ++r)
        Cb[(size_t)(row0 + wr * 128 + m * 16 + kg * 4 + r) * 1024 + col] = acc[m][n][r];
    }
  }
}

// ---------------------------------------------------------------------------
// rcp: colinv[i] = 1 / sum_p part[p][i]   (8 planes; 64 blocks)
// ---------------------------------------------------------------------------
__global__ __launch_bounds__(256) void rcp_kernel(const float* __restrict__ part,
                                                  float* __restrict__ ci) {
  const int i = blockIdx.x * 256 + threadIdx.x;
  float s = 0.f;
#pragma unroll
  for (int p = 0; p < 8; ++p) s += part[p * 16384 + i];
  ci[i] = 1.0f / s;
}

// ---------------------------------------------------------------------------
// scale: awbf = bf16(Xbf * colinv) in-place (swz8, same slot), aw fp32 out
// ---------------------------------------------------------------------------
__global__ __launch_bounds__(256) void scale_v1(short* __restrict__ Xbf,
                                                const float* __restrict__ colinv,
                                                float* __restrict__ aw) {
  const size_t gid = (size_t)blockIdx.x * 256 + threadIdx.x;
  const int rg = (int)(gid >> 7);
  const int ss = (int)(gid & 127);
  const int b = rg >> 10;
  const int gl = (ss & ~7) | ((ss & 7) ^ (rg & 7));   // logical granule
  const int h0 = gl * 8;
  short* p = Xbf + (size_t)rg * 1024 + ss * 8;
  const short8 v = *(const short8*)p;
  const float4 ci0 = *(const float4*)(colinv + (b << 10) + h0);
  const float4 ci1 = *(const float4*)(colinv + (b << 10) + h0 + 4);
  float f[8];
  f[0] = b2f((unsigned short)v[0]) * ci0.x; f[1] = b2f((unsigned short)v[1]) * ci0.y;
  f[2] = b2f((unsigned short)v[2]) * ci0.z; f[3] = b2f((unsigned short)v[3]) * ci0.w;
  f[4] = b2f((unsigned short)v[4]) * ci1.x; f[5] = b2f((unsigned short)v[5]) * ci1.y;
  f[6] = b2f((unsigned short)v[6]) * ci1.z; f[7] = b2f((unsigned short)v[7]) * ci1.w;
  float4 o0 = {f[0], f[1], f[2], f[3]};
  float4 o1 = {f[4], f[5], f[6], f[7]};
  *(float4*)(aw + (size_t)rg * 1024 + h0) = o0;
  *(float4*)(aw + (size_t)rg * 1024 + h0 + 4) = o1;
  short8 r;
#pragma unroll
  for (int j = 0; j < 8; ++j) r[j] = bfr(f[j]);
  *(short8*)p = r;
}

// ===========================================================================
// Fallback path (no workspace needed): R6/R7-proven kernels
// ===========================================================================
__global__ __launch_bounds__(256) void energy_mfma4(const short* __restrict__ enc_bf,
                                                    const short* __restrict__ W2_bf,
                                                    const float* __restrict__ c1,
                                                    float* __restrict__ X) {
  __shared__ __align__(16) short Ast[128 * 64];
  __shared__ __align__(16) short Bst[128 * 64];
  const int flat = blockIdx.x + (blockIdx.y << 3) + (blockIdx.z << 6);
  const int swz = (flat & 7) * 128 + (flat >> 3);
  const int b = swz >> 6;
  const int row0 = ((swz >> 3) & 7) * 128;
  const int col0 = (swz & 7) * 128;
  const int t = threadIdx.x;
  const int l = t & 63;
  const int w = t >> 6;
  const int wr = w >> 1, wc = w & 1;
  const int fr = l & 15, kg = l >> 4;

  const short* Abase = enc_bf + (size_t)b * SH + (size_t)(row0 + w * 32 + (l >> 3)) * 1024 + (l & 7) * 8;
  const short* Bbase = W2_bf + (size_t)(col0 + w * 32 + (l >> 3)) * 1024 + (l & 7) * 8;
  short* Alds = Ast + w * 2048;
  short* Blds = Bst + w * 2048;

  f32x4 acc[4][4] = {};

  for (int k0 = 0; k0 < 1024; k0 += 64) {
#pragma unroll
    for (int j = 0; j < 4; ++j) {
      GLD16(Abase + k0 + j * 8 * 1024, Alds + j * 512);
      GLD16(Bbase + k0 + j * 8 * 1024, Blds + j * 512);
    }
    __syncthreads();
#pragma unroll
    for (int kk = 0; kk < 2; ++kk) {
      short8 af[4], bf4[4];
#pragma unroll
      for (int m = 0; m < 4; ++m) {
        const int r = wr * 64 + m * 16 + fr;
        af[m] = *(const short8*)&Ast[r * 64 + (((kk * 4 + kg) ^ (r & 7)) << 3)];
      }
#pragma unroll
      for (int n = 0; n < 4; ++n) {
        const int r = wc * 64 + n * 16 + fr;
        bf4[n] = *(const short8*)&Bst[r * 64 + (((kk * 4 + kg) ^ (r & 7)) << 3)];
      }
#pragma unroll
      for (int m = 0; m < 4; ++m)
#pragma unroll
        for (int n = 0; n < 4; ++n)
          acc[m][n] = __builtin_amdgcn_mfma_f32_16x16x32_bf16(af[m], bf4[n], acc[m][n], 0, 0, 0);
    }
    __syncthreads();
  }

  float* Xb = X + (size_t)b * SH;
#pragma unroll
  for (int n = 0; n < 4; ++n) {
    const int col = col0 + wc * 64 + n * 16 + fr;
    const float c1v = c1[b * 1024 + col];
#pragma unroll
    for (int m = 0; m < 4; ++m) {
      const int r0 = row0 + wr * 64 + m * 16 + kg * 4;
#pragma unroll
      for (int r = 0; r < 4; ++r)
        Xb[(size_t)(r0 + r) * 1024 + col] = exptanh(acc[m][n][r] + c1v);
    }
  }
}

__global__ __launch_bounds__(256) void norm_kernel(float* __restrict__ X) {
  const int b = blockIdx.x >> 4;
  const int hg = blockIdx.x & 15;
  const int l = threadIdx.x & 63;
  const int sg = threadIdx.x >> 6;
  float* col = X + (size_t)b * SH + hg * 64 + l;
  const int s0 = sg * 256;
  float sum = 0.f;
#pragma unroll 8
  for (int s = s0; s < s0 + 256; ++s) sum += col[(size_t)s * 1024];
  __shared__ float red[4][64];
  red[sg][l] = sum;
  __syncthreads();
  const float inv = 1.f / (red[0][l] + red[1][l] + red[2][l] + red[3][l]);
#pragma unroll 8
  for (int s = s0; s < s0 + 256; ++s) col[(size_t)s * 1024] *= inv;
}

// self-contained fallback GEMM2 (raw fp32 inputs)
__global__ __launch_bounds__(256) void context_mfma(const float* __restrict__ aw,
                                                    const float* __restrict__ enc,
                                                    float* __restrict__ ctx) {
  __shared__ __align__(16) short Ast[128 * 32];
  __shared__ __align__(16) short Bst[128 * 32];
  const int b = blockIdx.z;
  const int row0 = blockIdx.y * 128;
  const int col0 = blockIdx.x * 128;
  const int t = threadIdx.x;
  const int l = t & 63;
  const int w = t >> 6;
  const int wr = w >> 1, wc = w & 1;
  const int fr = l & 15, kg = l >> 4;

  const int sr = t >> 1;
  const int sc0 = (t & 1) * 2;
  const float* arow = aw + (size_t)b * SH + (size_t)(row0 + sr) * 1024;
  const int bcol = t & 127;
  const int kb0 = (t >> 7) * 2;
  const float* bcolp = enc + (size_t)b * SH + col0 + bcol;

  f32x4 acc[4][4] = {};

#define LSLOT(r, g) ((r) * 32 + (((g) ^ (((r) >> 1) & 3)) << 3))
  for (int k0 = 0; k0 < 1024; k0 += 32) {
    const float4 a0 = *(const float4*)(arow + k0 + sc0 * 8);
    const float4 a1 = *(const float4*)(arow + k0 + sc0 * 8 + 4);
    const float4 a2 = *(const float4*)(arow + k0 + sc0 * 8 + 8);
    const float4 a3 = *(const float4*)(arow + k0 + sc0 * 8 + 12);
    float bv[2][8];
#pragma unroll
    for (int j = 0; j < 2; ++j)
#pragma unroll
      for (int i = 0; i < 8; ++i)
        bv[j][i] = bcolp[(size_t)(k0 + (kb0 + j) * 8 + i) * 1024];
    __syncthreads();
    *(short8*)&Ast[LSLOT(sr, sc0)]     = cvt8(a0, a1);
    *(short8*)&Ast[LSLOT(sr, sc0 + 1)] = cvt8(a2, a3);
#pragma unroll
    for (int j = 0; j < 2; ++j) {
      short8 pk;
#pragma unroll
      for (int i = 0; i < 8; ++i) pk[i] = bfr(bv[j][i]);
      *(short8*)&Bst[LSLOT(bcol, kb0 + j)] = pk;
    }
    __syncthreads();
    short8 af[4], bf4[4];
#pragma unroll
    for (int m = 0; m < 4; ++m) {
      const int r = wr * 64 + m * 16 + fr;
      af[m] = *(const short8*)&Ast[LSLOT(r, kg)];
    }
#pragma unroll
    for (int n = 0; n < 4; ++n) {
      const int r = wc * 64 + n * 16 + fr;
      bf4[n] = *(const short8*)&Bst[LSLOT(r, kg)];
    }
#pragma unroll
    for (int m = 0; m < 4; ++m)
#pragma unroll
      for (int n = 0; n < 4; ++n)
        acc[m][n] = __builtin_amdgcn_mfma_f32_16x16x32_bf16(af[m], bf4[n], acc[m][n], 0, 0, 0);
  }

  float* Cb = ctx + (size_t)b * SH;
#pragma unroll
  for (int n = 0; n < 4; ++n) {
    const int col = col0 + wc * 64 + n * 16 + fr;
#pragma unroll
    for (int m = 0; m < 4; ++m) {
      const int r0 = row0 + wr * 64 + m * 16 + kg * 4;
#pragma unroll
      for (int r = 0; r < 4; ++r)
        Cb[(size_t)(r0 + r) * 1024 + col] = acc[m][n][r];
    }
  }
}

// ---------------------------------------------------------------------------
extern "C" void kernel_launch(void* const* d_in, const int* in_sizes, int n_in,
                              void* d_out, int out_size, void* d_ws, size_t ws_size,
                              hipStream_t stream) {
  (void)in_sizes; (void)n_in; (void)out_size;
  const float* ht     = (const float*)d_in[0];
  const float* enc    = (const float*)d_in[1];
  const float* W_attn = (const float*)d_in[2];
  const float* b_attn = (const float*)d_in[3];
  // d_in[4] (W_v) is dead code in the reference

  float* ctx = (float*)d_out;          // [B,S,H] context (written last)
  float* aw  = ctx + BSH;              // [B,S,H] attention_weights

  // scratch parked inside the (dead-until-GEMM2) ctx region:
  short* enc_bf = (short*)ctx;                         // 32 MB, bf16 swz8
  short* W2_bf  = (short*)(ctx + 8388608);             // 2 MB
  float* c1f    = ctx + 8912896;                       // 64 KB
  float* part   = c1f + 16384;                         // 8 x 64 KB partial sums
  float* colinv = part + 8 * 16384;                    // 64 KB

  const bool ws2 = ws_size >= ((size_t)64 << 20);      // encT + Xbf
  short* encT = (short*)d_ws;                          // 32 MB
  short* Xbf  = (short*)((char*)d_ws + ((size_t)32 << 20));  // 32 MB

  if (ws2) {
    prep_kernel<<<4352, 256, 0, stream>>>(enc, ht, W_attn, b_attn,
                                          enc_bf, encT, c1f, W2_bf);
    energy8<<<256, 512, 0, stream>>>(enc_bf, W2_bf, c1f, Xbf, part);
    rcp_kernel<<<64, 256, 0, stream>>>(part, colinv);
    scale_v1<<<8192, 256, 0, stream>>>(Xbf, colinv, aw);
    context8<<<256, 512, 0, stream>>>(Xbf, encT, ctx);
  } else {
    c1w2_kernel<<<Hn / 4, 256, 0, stream>>>(ht, W_attn, b_attn, c1f, W2_bf);
    cvt_enc_kernel<<<8192, 256, 0, stream>>>(enc, enc_bf);
    dim3 g(8, 8, Bn);
    energy_mfma4<<<g, 256, 0, stream>>>(enc_bf, W2_bf, c1f, aw);
    norm_kernel<<<Bn * 16, 256, 0, stream>>>(aw);
    context_mfma<<<g, 256, 0, stream>>>(aw, enc, ctx);
  }
}

// Round 14
// 154.898 us; speedup vs baseline: 1.1130x; 1.0058x over previous
//
#include <hip/hip_runtime.h>
#include <math.h>

#define Bn 16
#define Sn 1024
#define Hn 1024
static const size_t SH = (size_t)Sn * Hn;          // 1,048,576
static const size_t BSH = (size_t)Bn * Sn * Hn;    // 16,777,216

typedef __attribute__((ext_vector_type(8))) short short8;
typedef __attribute__((ext_vector_type(4))) float f32x4;

// async global->LDS, 16B per lane; LDS dest is wave-uniform base + lane*16
#define GLD16(gp, lp) __builtin_amdgcn_global_load_lds( \
    (const __attribute__((address_space(1))) void*)(gp), \
    (__attribute__((address_space(3))) void*)(lp), 16, 0, 0)

// round-to-nearest-even fp32 -> bf16
__device__ __forceinline__ short bfr(float f) {
  union { float f; unsigned u; } v; v.f = f;
  unsigned r = (v.u + 0x7FFFu + ((v.u >> 16) & 1u)) >> 16;
  return (short)r;
}
__device__ __forceinline__ float b2f(unsigned short u) {
  union { unsigned u; float f; } v; v.u = (unsigned)u << 16; return v.f;
}
__device__ __forceinline__ short8 cvt8(float4 x, float4 y) {
  short8 r;
  r[0] = bfr(x.x); r[1] = bfr(x.y); r[2] = bfr(x.z); r[3] = bfr(x.w);
  r[4] = bfr(y.x); r[5] = bfr(y.y); r[6] = bfr(y.z); r[7] = bfr(y.w);
  return r;
}
// X = exp(tanh(x)) with fast rcp: tanh = 1 - 2/(e^{2x}+1)
__device__ __forceinline__ float exptanh(float x) {
  const float e = __expf(2.f * x);
  const float r = __builtin_amdgcn_rcpf(e + 1.f);
  return __expf(1.f - 2.f * r);
}

// 8-granule swizzle: storage slot of logical granule g in row `row` is
// g ^ (row&7) within each 8-granule (64-element) k-block. Involution.
__device__ __forceinline__ int swz8(int row, int g) {
  return (g & ~7) | ((g & 7) ^ (row & 7));
}

// ---------------------------------------------------------------------------
// prep: ONE launch doing both
//   blocks [0,4096):   fused_cvt — enc -> enc_bf (swz8) AND encT (swz8)
//   blocks [4096,4352): c1 + W2 cvt — c1[b,h], W2_bf[h] (swz8)
// ---------------------------------------------------------------------------
__global__ __launch_bounds__(256) void prep_kernel(const float* __restrict__ enc,
                                                   const float* __restrict__ ht,
                                                   const float* __restrict__ W_attn,
                                                   const float* __restrict__ b_attn,
                                                   short* __restrict__ enc_bf,
                                                   short* __restrict__ encT,
                                                   float* __restrict__ c1,
                                                   short* __restrict__ W2_bf) {
  __shared__ float smem[4160];   // 16.6 KB, union: cvt tile / c1 ht-chunk
  const int blk = blockIdx.x;
  const int t = threadIdx.x;

  if (blk < 4096) {
    // ---- fused_cvt tile ----
    float (*tile)[65] = (float(*)[65])smem;
    const int b = blk >> 8;
    const int s0 = ((blk >> 4) & 15) * 64, h0 = (blk & 15) * 64;
    const int tr = t >> 4, tc = t & 15;
    const float* src = enc + (size_t)b * SH;
#pragma unroll
    for (int i = 0; i < 4; ++i) {
      const int s = i * 16 + tr;
      const float4 v = *(const float4*)(src + (size_t)(s0 + s) * 1024 + h0 + tc * 4);
      tile[s][tc * 4 + 0] = v.x; tile[s][tc * 4 + 1] = v.y;
      tile[s][tc * 4 + 2] = v.z; tile[s][tc * 4 + 3] = v.w;
    }
    __syncthreads();
    {
      const int rloc = t >> 2;
      const int rg = b * 1024 + s0 + rloc;
#pragma unroll
      for (int jj = 0; jj < 2; ++jj) {
        const int jloc = (t & 3) * 2 + jj;
        const int slot = jloc ^ (rg & 7);
        const float4 x = *(const float4*)&tile[rloc][jloc * 8];
        const float4 y = *(const float4*)&tile[rloc][jloc * 8 + 4];
        *(short8*)(enc_bf + (size_t)rg * 1024 + h0 + slot * 8) = cvt8(x, y);
      }
    }
    {
      const int hr = t >> 2, cs = t & 3;
      const int h = h0 + hr;
#pragma unroll
      for (int blkj = 0; blkj < 2; ++blkj) {
        const int sg = blkj * 4 + cs;
        const int gl = (s0 >> 3) + sg;
        const int gst = swz8(h, gl);
        short8 pk;
#pragma unroll
        for (int j = 0; j < 8; ++j) pk[j] = bfr(tile[sg * 8 + j][hr]);
        *(short8*)(encT + (size_t)b * SH + (size_t)h * 1024 + gst * 8) = pk;
      }
    }
  } else {
    // ---- c1 + W2 cvt (k-chunked ht staging, 16 KB) ----
    float* hts = smem;            // [16 batches][256 k] = 4096 floats
    const int bid = blk - 4096;
    const int h = bid * 4 + (t >> 6);
    const int lane = t & 63;
    const float* w = W_attn + (size_t)h * 2048;
    {
      const float* w2 = w + 1024;
#pragma unroll
      for (int j = 0; j < 2; ++j) {
        const int cs = lane * 2 + j;
        const float4 x = *(const float4*)(w2 + cs * 8);
        const float4 y = *(const float4*)(w2 + cs * 8 + 4);
        *(short8*)(W2_bf + (size_t)h * 1024 + swz8(h, cs) * 8) = cvt8(x, y);
      }
    }
    float s[16];
#pragma unroll
    for (int b = 0; b < 16; ++b) s[b] = 0.f;
    for (int c = 0; c < 4; ++c) {
#pragma unroll
      for (int i = 0; i < 4; ++i) {
        const int idx = i * 1024 + t * 4;          // 0..4095
        const int b = idx >> 8, k = idx & 255;
        *(float4*)&hts[idx] = *(const float4*)&ht[b * 1024 + c * 256 + k];
      }
      __syncthreads();
#pragma unroll
      for (int ki = 0; ki < 4; ++ki) {
        const int k = ki * 64 + lane;
        const float wv = w[c * 256 + k];
#pragma unroll
        for (int b = 0; b < 16; ++b) s[b] = fmaf(wv, hts[b * 256 + k], s[b]);
      }
      __syncthreads();   // protect hts overwrite next chunk
    }
#pragma unroll
    for (int b = 0; b < 16; ++b) {
      float v = s[b];
#pragma unroll
      for (int off = 32; off; off >>= 1) v += __shfl_down(v, off, 64);
      if (lane == 0) c1[b * 1024 + h] = v + b_attn[h];
    }
  }
}

// ---------------------------------------------------------------------------
// cvt_enc (fallback): enc -> enc_bf, swz8
// ---------------------------------------------------------------------------
__global__ __launch_bounds__(256) void cvt_enc_kernel(const float* __restrict__ enc,
                                                      short* __restrict__ enc_bf) {
  const int g = blockIdx.x * 256 + threadIdx.x;
  const int row = g >> 7;
  const int cs = g & 127;
  const float4 x = *(const float4*)(enc + (size_t)row * 1024 + cs * 8);
  const float4 y = *(const float4*)(enc + (size_t)row * 1024 + cs * 8 + 4);
  *(short8*)(enc_bf + (size_t)row * 1024 + swz8(row, cs) * 8) = cvt8(x, y);
}

// ---------------------------------------------------------------------------
// c1w2 (fallback): c1[b,h] + W2 cvt, 64KB ht stage (standalone proven)
// ---------------------------------------------------------------------------
__global__ __launch_bounds__(256) void c1w2_kernel(const float* __restrict__ ht,
                                                   const float* __restrict__ W_attn,
                                                   const float* __restrict__ b_attn,
                                                   float* __restrict__ c1,
                                                   short* __restrict__ W2_bf) {
  __shared__ float hts[16384];
  const int t = threadIdx.x;
#pragma unroll
  for (int i = 0; i < 16; ++i)
    *(float4*)&hts[i * 1024 + t * 4] = *(const float4*)&ht[i * 1024 + t * 4];
  __syncthreads();
  const int h = blockIdx.x * 4 + (t >> 6);
  const int lane = t & 63;
  const float* w = W_attn + (size_t)h * 2048;
  {
    const float* w2 = w + 1024;
#pragma unroll
    for (int j = 0; j < 2; ++j) {
      const int cs = lane * 2 + j;
      const float4 x = *(const float4*)(w2 + cs * 8);
      const float4 y = *(const float4*)(w2 + cs * 8 + 4);
      *(short8*)(W2_bf + (size_t)h * 1024 + swz8(h, cs) * 8) = cvt8(x, y);
    }
  }
  float s[16];
#pragma unroll
  for (int b = 0; b < 16; ++b) s[b] = 0.f;
  for (int k = lane; k < 1024; k += 64) {
    const float wv = w[k];
#pragma unroll
    for (int b = 0; b < 16; ++b) s[b] = fmaf(wv, hts[b * 1024 + k], s[b]);
  }
#pragma unroll
  for (int b = 0; b < 16; ++b) {
    float v = s[b];
#pragma unroll
    for (int off = 32; off; off >>= 1) v += __shfl_down(v, off, 64);
    if (lane == 0) c1[b * 1024 + h] = v + b_attn[h];
  }
}

// ===========================================================================
// 8-phase 256x256 GEMM template (m201-style, plain HIP).
// PROVEN race-free across graph replays (R9/R11/R12/R13). Byte-identical.
// ===========================================================================
#define STAGE_A(kt, mh) do {                                              \
  const int p_ = (kt) & 1;                                                \
  _Pragma("unroll") for (int ld_ = 0; ld_ < 2; ++ld_) {                   \
    const int rl_ = (ld_ * 8 + wid) * 8 + (l >> 3);                       \
    GLD16(Ag + (size_t)((rl_ >> 6) * 128 + (mh) * 64 + (rl_ & 63)) * 1024 \
             + (kt) * 64 + (l & 7) * 8,                                   \
          &lds[p_ * 32768 + (mh) * 8192 + (ld_ * 8 + wid) * 512]);        \
  } } while (0)

#define STAGE_B(kt, nh) do {                                              \
  const int p_ = (kt) & 1;                                                \
  _Pragma("unroll") for (int ld_ = 0; ld_ < 2; ++ld_) {                   \
    const int rl_ = (ld_ * 8 + wid) * 8 + (l >> 3);                       \
    GLD16(Bg + (size_t)((rl_ >> 5) * 64 + (nh) * 32 + (rl_ & 31)) * 1024  \
             + (kt) * 64 + (l & 7) * 8,                                   \
          &lds[16384 + p_ * 32768 + (nh) * 8192 + (ld_ * 8 + wid) * 512]); \
  } } while (0)

#define PHASE(mh, nh, ...) do {                                           \
  if ((nh) == 0) {                                                        \
    _Pragma("unroll") for (int mi = 0; mi < 4; ++mi)                      \
      _Pragma("unroll") for (int ks = 0; ks < 2; ++ks)                    \
        afr[mi][ks] = *(const short8*)&lds[ab + (mh) * 8192               \
            + (wr * 64 + mi * 16 + fr) * 64                               \
            + (((ks * 4 + kg) ^ (fr & 7)) << 3)];                         \
  }                                                                       \
  _Pragma("unroll") for (int ni = 0; ni < 2; ++ni)                        \
    _Pragma("unroll") for (int ks = 0; ks < 2; ++ks)                      \
      bfrg[ni][ks] = *(const short8*)&lds[bb + (nh) * 8192                \
          + (wc * 32 + ni * 16 + fr) * 64                                 \
          + (((ks * 4 + kg) ^ (fr & 7)) << 3)];                           \
  __VA_ARGS__;                                                            \
  __builtin_amdgcn_s_barrier();                                           \
  __builtin_amdgcn_s_setprio(1);                                          \
  _Pragma("unroll") for (int mi = 0; mi < 4; ++mi)                        \
    _Pragma("unroll") for (int ni = 0; ni < 2; ++ni)                      \
      _Pragma("unroll") for (int ks = 0; ks < 2; ++ks)                    \
        acc[(mh) * 4 + mi][(nh) * 2 + ni] =                               \
            __builtin_amdgcn_mfma_f32_16x16x32_bf16(afr[mi][ks],          \
                bfrg[ni][ks], acc[(mh) * 4 + mi][(nh) * 2 + ni], 0, 0, 0); \
  __builtin_amdgcn_s_setprio(0);                                          \
} while (0)

#define KLOOP_8PHASE()                                                    \
  STAGE_A(0, 0); STAGE_B(0, 0); STAGE_B(0, 1); STAGE_A(0, 1);             \
  STAGE_A(1, 0); STAGE_B(1, 0);                                           \
  asm volatile("s_waitcnt vmcnt(4)" ::: "memory");                        \
  __builtin_amdgcn_s_barrier();                                           \
  _Pragma("unroll 2") for (int kt = 0; kt < 16; ++kt) {                   \
    const int ab = (kt & 1) * 32768;                                      \
    const int bb = 16384 + (kt & 1) * 32768;                              \
    PHASE(0, 0, if (kt < 15) STAGE_B(kt + 1, 1));                         \
    __builtin_amdgcn_s_barrier();                                         \
    PHASE(0, 1, if (kt < 15) STAGE_A(kt + 1, 1));                         \
    __builtin_amdgcn_s_barrier();                                         \
    PHASE(1, 0, if (kt < 14) STAGE_A(kt + 2, 0));                         \
    __builtin_amdgcn_s_barrier();                                         \
    PHASE(1, 1, if (kt < 14) STAGE_B(kt + 2, 0));                         \
    if (kt < 14) asm volatile("s_waitcnt vmcnt(4)" ::: "memory");         \
    else         asm volatile("s_waitcnt vmcnt(0)" ::: "memory");         \
    __builtin_amdgcn_s_barrier();                                         \
  }

// ---------------------------------------------------------------------------
// GEMM1 (8-phase): Xbf = bf16(exp(tanh(enc_bf . W2_bf^T + c1))) [swz8 layout]
// + per-(row_blk,wr) partial column sums. Rotation obuf (<=2-way banks).
// ---------------------------------------------------------------------------
__global__ __launch_bounds__(512) void energy8(const short* __restrict__ enc_bf,
                                               const short* __restrict__ W2_bf,
                                               const float* __restrict__ c1,
                                               short* __restrict__ Xbf,
                                               float* __restrict__ part) {
  __shared__ __align__(16) short lds[65536];   // 128 KB
  const int flat = blockIdx.x;
  const int id = (flat & 7) * 32 + (flat >> 3);   // XCD-chunked (256 = 8*32)
  const int b = id >> 4;
  const int rb = (id >> 2) & 3;
  const int row0 = rb * 256;
  const int col0 = (id & 3) * 256;
  const int t = threadIdx.x;
  const int wid = t >> 6, l = t & 63;
  const int wr = wid >> 2, wc = wid & 3;
  const int fr = l & 15, kg = l >> 4;

  const short* Ag = enc_bf + (size_t)b * SH + (size_t)row0 * 1024;
  const short* Bg = W2_bf + (size_t)col0 * 1024;

  f32x4 acc[8][4] = {};
  short8 afr[4][2], bfrg[2][2];

  KLOOP_8PHASE();
  __syncthreads();   // full fence before LDS reuse

  unsigned short* obuf = (unsigned short*)lds;   // 256x256 ushort = 128 KB
  float* pplane = part + (size_t)(rb * 2 + wr) * 16384 + b * 1024 + col0;
#pragma unroll
  for (int n = 0; n < 4; ++n) {
    const int col_loc = wc * 64 + n * 16 + fr;
    const float c1v = c1[b * 1024 + col0 + col_loc];
    float csum = 0.f;
#pragma unroll
    for (int m = 0; m < 8; ++m) {
#pragma unroll
      for (int r = 0; r < 4; ++r) {
        const int row_loc = wr * 128 + m * 16 + kg * 4 + r;
        const float X = exptanh(acc[m][n][r] + c1v);
        csum += X;
        const int g = col_loc >> 3;
        const int s2 = (g + row_loc) & 31;       // rotation: bank-spread
        obuf[row_loc * 256 + s2 * 8 + (col_loc & 7)] = (unsigned short)bfr(X);
      }
    }
    csum += __shfl_xor(csum, 16);
    csum += __shfl_xor(csum, 32);
    if (l < 16) pplane[col_loc] = csum;
  }
  __syncthreads();
  // copy-out: global slot q holds logical granule gq = (q&~7)|((q&7)^(row&7))
  // which lives at LDS slot (gq+row)&31.
  const int orow = t >> 1;
  short* gd = Xbf + (size_t)b * SH + (size_t)(row0 + orow) * 1024 + col0;
#pragma unroll
  for (int j = 0; j < 16; ++j) {
    const int q = (t & 1) * 16 + j;
    const int gq = (q & ~7) | ((q & 7) ^ (orow & 7));
    const int ls = (gq + orow) & 31;
    *(short8*)(gd + q * 8) = *(short8*)&obuf[orow * 256 + ls * 8];
  }
}

// ---------------------------------------------------------------------------
// GEMM2 (8-phase): ctx = awbf . encT^T
// NEW epilogue: two-half LDS bounce -> fully coalesced fp32 copy-out
// (1KB-contiguous per wave) instead of 64B half-line direct stores.
// ---------------------------------------------------------------------------
__global__ __launch_bounds__(512) void context8(const short* __restrict__ awbf,
                                                const short* __restrict__ encT,
                                                float* __restrict__ ctx) {
  __shared__ __align__(16) short lds[65536];
  const int flat = blockIdx.x;
  const int id = (flat & 7) * 32 + (flat >> 3);
  const int b = id >> 4;
  const int row0 = ((id >> 2) & 3) * 256;
  const int col0 = (id & 3) * 256;
  const int t = threadIdx.x;
  const int wid = t >> 6, l = t & 63;
  const int wr = wid >> 2, wc = wid & 3;
  const int fr = l & 15, kg = l >> 4;

  const short* Ag = awbf + (size_t)b * SH + (size_t)row0 * 1024;
  const short* Bg = encT + (size_t)b * SH + (size_t)col0 * 1024;

  f32x4 acc[8][4] = {};
  short8 afr[4][2], bfrg[2][2];

  KLOOP_8PHASE();

  // --- two-half bounced C-write ---
  // obuf fp32 [128][256] = 128 KB. Half h (= wr) stores with float4-unit XOR
  // (col4 ^ (row&7)) for bank spread; all 512 threads copy out linearly.
  float* obuf = (float*)lds;
  float* Cb = ctx + (size_t)b * SH;
#pragma unroll
  for (int half = 0; half < 2; ++half) {
    __syncthreads();   // prior LDS use done (K-loop bufs / previous half)
    if (wr == half) {
#pragma unroll
      for (int n = 0; n < 4; ++n) {
        const int col = wc * 64 + n * 16 + fr;
#pragma unroll
        for (int m = 0; m < 8; ++m) {
#pragma unroll
          for (int r = 0; r < 4; ++r) {
            const int row = m * 16 + kg * 4 + r;   // 0..127 within half
            const int c4x = ((col >> 2) ^ (row & 7)) * 4 + (col & 3);
            obuf[row * 256 + c4x] = acc[m][n][r];
          }
        }
      }
    }
    __syncthreads();
    // linear copy-out: 32768 floats / 512 thr = 16 float4 each
#pragma unroll
    for (int jj = 0; jj < 16; ++jj) {
      const int fidx = jj * 2048 + t * 4;          // float index
      const int row = fidx >> 8;
      const int c4 = (fidx & 255) >> 2;
      const f32x4 v = *(const f32x4*)&obuf[row * 256 + (c4 ^ (row & 7)) * 4];
      *(f32x4*)&Cb[(size_t)(row0 + half * 128 + row) * 1024 + col0 + c4 * 4] = v;
    }
  }
}

// ---------------------------------------------------------------------------
// rcp: colinv[i] = 1 / sum_p part[p][i]   (8 planes; 64 blocks)
// ---------------------------------------------------------------------------
__global__ __launch_bounds__(256) void rcp_kernel(const float* __restrict__ part,
                                                  float* __restrict__ ci) {
  const int i = blockIdx.x * 256 + threadIdx.x;
  float s = 0.f;
#pragma unroll
  for (int p = 0; p < 8; ++p) s += part[p * 16384 + i];
  ci[i] = 1.0f / s;
}

// ---------------------------------------------------------------------------
// scale: awbf = bf16(Xbf * colinv) in-place (swz8, same slot), aw fp32 out
// ---------------------------------------------------------------------------
__global__ __launch_bounds__(256) void scale_v1(short* __restrict__ Xbf,
                                                const float* __restrict__ colinv,
                                                float* __restrict__ aw) {
  const size_t gid = (size_t)blockIdx.x * 256 + threadIdx.x;
  const int rg = (int)(gid >> 7);
  const int ss = (int)(gid & 127);
  const int b = rg >> 10;
  const int gl = (ss & ~7) | ((ss & 7) ^ (rg & 7));   // logical granule
  const int h0 = gl * 8;
  short* p = Xbf + (size_t)rg * 1024 + ss * 8;
  const short8 v = *(const short8*)p;
  const float4 ci0 = *(const float4*)(colinv + (b << 10) + h0);
  const float4 ci1 = *(const float4*)(colinv + (b << 10) + h0 + 4);
  float f[8];
  f[0] = b2f((unsigned short)v[0]) * ci0.x; f[1] = b2f((unsigned short)v[1]) * ci0.y;
  f[2] = b2f((unsigned short)v[2]) * ci0.z; f[3] = b2f((unsigned short)v[3]) * ci0.w;
  f[4] = b2f((unsigned short)v[4]) * ci1.x; f[5] = b2f((unsigned short)v[5]) * ci1.y;
  f[6] = b2f((unsigned short)v[6]) * ci1.z; f[7] = b2f((unsigned short)v[7]) * ci1.w;
  float4 o0 = {f[0], f[1], f[2], f[3]};
  float4 o1 = {f[4], f[5], f[6], f[7]};
  *(float4*)(aw + (size_t)rg * 1024 + h0) = o0;
  *(float4*)(aw + (size_t)rg * 1024 + h0 + 4) = o1;
  short8 r;
#pragma unroll
  for (int j = 0; j < 8; ++j) r[j] = bfr(f[j]);
  *(short8*)p = r;
}

// ===========================================================================
// Fallback path (no workspace needed): R6/R7-proven kernels
// ===========================================================================
__global__ __launch_bounds__(256) void energy_mfma4(const short* __restrict__ enc_bf,
                                                    const short* __restrict__ W2_bf,
                                                    const float* __restrict__ c1,
                                                    float* __restrict__ X) {
  __shared__ __align__(16) short Ast[128 * 64];
  __shared__ __align__(16) short Bst[128 * 64];
  const int flat = blockIdx.x + (blockIdx.y << 3) + (blockIdx.z << 6);
  const int swz = (flat & 7) * 128 + (flat >> 3);
  const int b = swz >> 6;
  const int row0 = ((swz >> 3) & 7) * 128;
  const int col0 = (swz & 7) * 128;
  const int t = threadIdx.x;
  const int l = t & 63;
  const int w = t >> 6;
  const int wr = w >> 1, wc = w & 1;
  const int fr = l & 15, kg = l >> 4;

  const short* Abase = enc_bf + (size_t)b * SH + (size_t)(row0 + w * 32 + (l >> 3)) * 1024 + (l & 7) * 8;
  const short* Bbase = W2_bf + (size_t)(col0 + w * 32 + (l >> 3)) * 1024 + (l & 7) * 8;
  short* Alds = Ast + w * 2048;
  short* Blds = Bst + w * 2048;

  f32x4 acc[4][4] = {};

  for (int k0 = 0; k0 < 1024; k0 += 64) {
#pragma unroll
    for (int j = 0; j < 4; ++j) {
      GLD16(Abase + k0 + j * 8 * 1024, Alds + j * 512);
      GLD16(Bbase + k0 + j * 8 * 1024, Blds + j * 512);
    }
    __syncthreads();
#pragma unroll
    for (int kk = 0; kk < 2; ++kk) {
      short8 af[4], bf4[4];
#pragma unroll
      for (int m = 0; m < 4; ++m) {
        const int r = wr * 64 + m * 16 + fr;
        af[m] = *(const short8*)&Ast[r * 64 + (((kk * 4 + kg) ^ (r & 7)) << 3)];
      }
#pragma unroll
      for (int n = 0; n < 4; ++n) {
        const int r = wc * 64 + n * 16 + fr;
        bf4[n] = *(const short8*)&Bst[r * 64 + (((kk * 4 + kg) ^ (r & 7)) << 3)];
      }
#pragma unroll
      for (int m = 0; m < 4; ++m)
#pragma unroll
        for (int n = 0; n < 4; ++n)
          acc[m][n] = __builtin_amdgcn_mfma_f32_16x16x32_bf16(af[m], bf4[n], acc[m][n], 0, 0, 0);
    }
    __syncthreads();
  }

  float* Xb = X + (size_t)b * SH;
#pragma unroll
  for (int n = 0; n < 4; ++n) {
    const int col = col0 + wc * 64 + n * 16 + fr;
    const float c1v = c1[b * 1024 + col];
#pragma unroll
    for (int m = 0; m < 4; ++m) {
      const int r0 = row0 + wr * 64 + m * 16 + kg * 4;
#pragma unroll
      for (int r = 0; r < 4; ++r)
        Xb[(size_t)(r0 + r) * 1024 + col] = exptanh(acc[m][n][r] + c1v);
    }
  }
}

__global__ __launch_bounds__(256) void norm_kernel(float* __restrict__ X) {
  const int b = blockIdx.x >> 4;
  const int hg = blockIdx.x & 15;
  const int l = threadIdx.x & 63;
  const int sg = threadIdx.x >> 6;
  float* col = X + (size_t)b * SH + hg * 64 + l;
  const int s0 = sg * 256;
  float sum = 0.f;
#pragma unroll 8
  for (int s = s0; s < s0 + 256; ++s) sum += col[(size_t)s * 1024];
  __shared__ float red[4][64];
  red[sg][l] = sum;
  __syncthreads();
  const float inv = 1.f / (red[0][l] + red[1][l] + red[2][l] + red[3][l]);
#pragma unroll 8
  for (int s = s0; s < s0 + 256; ++s) col[(size_t)s * 1024] *= inv;
}

// self-contained fallback GEMM2 (raw fp32 inputs)
__global__ __launch_bounds__(256) void context_mfma(const float* __restrict__ aw,
                                                    const float* __restrict__ enc,
                                                    float* __restrict__ ctx) {
  __shared__ __align__(16) short Ast[128 * 32];
  __shared__ __align__(16) short Bst[128 * 32];
  const int b = blockIdx.z;
  const int row0 = blockIdx.y * 128;
  const int col0 = blockIdx.x * 128;
  const int t = threadIdx.x;
  const int l = t & 63;
  const int w = t >> 6;
  const int wr = w >> 1, wc = w & 1;
  const int fr = l & 15, kg = l >> 4;

  const int sr = t >> 1;
  const int sc0 = (t & 1) * 2;
  const float* arow = aw + (size_t)b * SH + (size_t)(row0 + sr) * 1024;
  const int bcol = t & 127;
  const int kb0 = (t >> 7) * 2;
  const float* bcolp = enc + (size_t)b * SH + col0 + bcol;

  f32x4 acc[4][4] = {};

#define LSLOT(r, g) ((r) * 32 + (((g) ^ (((r) >> 1) & 3)) << 3))
  for (int k0 = 0; k0 < 1024; k0 += 32) {
    const float4 a0 = *(const float4*)(arow + k0 + sc0 * 8);
    const float4 a1 = *(const float4*)(arow + k0 + sc0 * 8 + 4);
    const float4 a2 = *(const float4*)(arow + k0 + sc0 * 8 + 8);
    const float4 a3 = *(const float4*)(arow + k0 + sc0 * 8 + 12);
    float bv[2][8];
#pragma unroll
    for (int j = 0; j < 2; ++j)
#pragma unroll
      for (int i = 0; i < 8; ++i)
        bv[j][i] = bcolp[(size_t)(k0 + (kb0 + j) * 8 + i) * 1024];
    __syncthreads();
    *(short8*)&Ast[LSLOT(sr, sc0)]     = cvt8(a0, a1);
    *(short8*)&Ast[LSLOT(sr, sc0 + 1)] = cvt8(a2, a3);
#pragma unroll
    for (int j = 0; j < 2; ++j) {
      short8 pk;
#pragma unroll
      for (int i = 0; i < 8; ++i) pk[i] = bfr(bv[j][i]);
      *(short8*)&Bst[LSLOT(bcol, kb0 + j)] = pk;
    }
    __syncthreads();
    short8 af[4], bf4[4];
#pragma unroll
    for (int m = 0; m < 4; ++m) {
      const int r = wr * 64 + m * 16 + fr;
      af[m] = *(const short8*)&Ast[LSLOT(r, kg)];
    }
#pragma unroll
    for (int n = 0; n < 4; ++n) {
      const int r = wc * 64 + n * 16 + fr;
      bf4[n] = *(const short8*)&Bst[LSLOT(r, kg)];
    }
#pragma unroll
    for (int m = 0; m < 4; ++m)
#pragma unroll
      for (int n = 0; n < 4; ++n)
        acc[m][n] = __builtin_amdgcn_mfma_f32_16x16x32_bf16(af[m], bf4[n], acc[m][n], 0, 0, 0);
  }

  float* Cb = ctx + (size_t)b * SH;
#pragma unroll
  for (int n = 0; n < 4; ++n) {
    const int col = col0 + wc * 64 + n * 16 + fr;
#pragma unroll
    for (int m = 0; m < 4; ++m) {
      const int r0 = row0 + wr * 64 + m * 16 + kg * 4;
#pragma unroll
      for (int r = 0; r < 4; ++r)
        Cb[(size_t)(r0 + r) * 1024 + col] = acc[m][n][r];
    }
  }
}

// ---------------------------------------------------------------------------
extern "C" void kernel_launch(void* const* d_in, const int* in_sizes, int n_in,
                              void* d_out, int out_size, void* d_ws, size_t ws_size,
                              hipStream_t stream) {
  (void)in_sizes; (void)n_in; (void)out_size;
  const float* ht     = (const float*)d_in[0];
  const float* enc    = (const float*)d_in[1];
  const float* W_attn = (const float*)d_in[2];
  const float* b_attn = (const float*)d_in[3];
  // d_in[4] (W_v) is dead code in the reference

  float* ctx = (float*)d_out;          // [B,S,H] context (written last)
  float* aw  = ctx + BSH;              // [B,S,H] attention_weights

  // scratch parked inside the (dead-until-GEMM2) ctx region:
  short* enc_bf = (short*)ctx;                         // 32 MB, bf16 swz8
  short* W2_bf  = (short*)(ctx + 8388608);             // 2 MB
  float* c1f    = ctx + 8912896;                       // 64 KB
  float* part   = c1f + 16384;                         // 8 x 64 KB partial sums
  float* colinv = part + 8 * 16384;                    // 64 KB

  const bool ws2 = ws_size >= ((size_t)64 << 20);      // encT + Xbf
  short* encT = (short*)d_ws;                          // 32 MB
  short* Xbf  = (short*)((char*)d_ws + ((size_t)32 << 20));  // 32 MB

  if (ws2) {
    prep_kernel<<<4352, 256, 0, stream>>>(enc, ht, W_attn, b_attn,
                                          enc_bf, encT, c1f, W2_bf);
    energy8<<<256, 512, 0, stream>>>(enc_bf, W2_bf, c1f, Xbf, part);
    rcp_kernel<<<64, 256, 0, stream>>>(part, colinv);
    scale_v1<<<8192, 256, 0, stream>>>(Xbf, colinv, aw);
    context8<<<256, 512, 0, stream>>>(Xbf, encT, ctx);
  } else {
    c1w2_kernel<<<Hn / 4, 256, 0, stream>>>(ht, W_attn, b_attn, c1f, W2_bf);
    cvt_enc_kernel<<<8192, 256, 0, stream>>>(enc, enc_bf);
    dim3 g(8, 8, Bn);
    energy_mfma4<<<g, 256, 0, stream>>>(enc_bf, W2_bf, c1f, aw);
    norm_kernel<<<Bn * 16, 256, 0, stream>>>(aw);
    context_mfma<<<g, 256, 0, stream>>>(aw, enc, ctx);
  }
}